// Round 8
// baseline (290.285 us; speedup 1.0000x reference)
//
#include <hip/hip_runtime.h>
#include <hip/hip_bf16.h>

#define HW 65536
#define GNS 128

typedef __attribute__((ext_vector_type(8))) short short8;
typedef __attribute__((ext_vector_type(4))) float f32x4;
union U8 { short8 s; unsigned u[4]; ushort h[8]; };

static __device__ __forceinline__ ushort f2bf(float f) {
    union { float f; unsigned u; } v; v.f = f;
    unsigned u = v.u;
    unsigned r = (u + 0x7fffu + ((u >> 16) & 1u)) >> 16;
    return (ushort)r;
}
static __device__ __forceinline__ float bf2f(ushort u) {
    union { unsigned u; float f; } v; v.u = ((unsigned)u) << 16; return v.f;
}
static __device__ __forceinline__ unsigned pk2(float a, float b) {
    __hip_bfloat162 h = __float22bfloat162_rn(make_float2(a, b));
    union { __hip_bfloat162 h; unsigned u; } c; c.h = h; return c.u;
}
static __device__ __forceinline__ f32x4 mfma16(short8 a, short8 b, f32x4 c) {
    return __builtin_amdgcn_mfma_f32_16x16x32_bf16(a, b, c, 0, 0, 0);
}

// ---------------- prep: pack conv weights bf16; fold W1/W2; zero SSQ ----------------
__global__ __launch_bounds__(256) void prep_kernel(
        const float* __restrict__ qc, const float* __restrict__ kvc,
        const float* __restrict__ qt, const float* __restrict__ kvt,
        const float* __restrict__ cw, const float* __restrict__ poc, const float* __restrict__ pot,
        ushort* __restrict__ Wc, ushort* __restrict__ Wt,
        float* __restrict__ W1, float* __restrict__ W2, float* __restrict__ SSQ) {
    int bx = blockIdx.x, tid = threadIdx.x;
    if (bx < 9) {
        for (int idx = bx * 256 + tid; idx < 288 * 96; idx += 9 * 256) {
            Wc[idx] = f2bf(idx < 96 * 96 ? qc[idx] : kvc[idx - 96 * 96]);
            Wt[idx] = f2bf(idx < 96 * 96 ? qt[idx] : kvt[idx - 96 * 96]);
        }
        if (bx == 0)
            for (int idx = tid; idx < 8 * 96; idx += 256) SSQ[idx] = 0.f;
    } else {
        int idx = (bx - 9) * 256 + tid;          // 0..18431
        int sel = idx < 9216 ? 0 : 1;
        int i = sel ? idx - 9216 : idx;
        int o = i / 96, m = i % 96;
        const float* po = sel ? pot : poc;
        float acc = 0.f;
        for (int p = 0; p < 96; ++p)
            acc += cw[o * 192 + sel * 96 + p] * po[p * 96 + m];
        (sel ? W2 : W1)[i] = acc;
    }
}

// ---------------- conv1x1: MFMA loop -> LDS restage -> contiguous stores ----------------
__global__ __launch_bounds__(256, 2) void conv_kernel(const float* __restrict__ X,
                                                      const ushort* __restrict__ W,
                                                      ushort* __restrict__ Y) {
    __shared__ ushort xs[96][136];                // staging, reused as output restage
    int tid = threadIdx.x;
    int n0 = blockIdx.x * 128;
    int og = blockIdx.y;                          // 0..2 (o-group of 96)
    int b = blockIdx.z;
    int wave = tid >> 6, lane = tid & 63, lr = lane & 15, lg = lane >> 4;
    const float* Xb = X + (size_t)b * 96 * HW + n0;
    #pragma unroll
    for (int i = 0; i < 12; ++i) {
        int idx = tid + i * 256;                  // 3072 = 96 ch x 32 quads
        int ch = idx >> 5, g = idx & 31;
        float4 v = *(const float4*)(Xb + (size_t)ch * HW + 4 * g);
        unsigned* d = (unsigned*)&xs[ch][4 * g];
        d[0] = pk2(v.x, v.y);
        d[1] = pk2(v.z, v.w);
    }
    __syncthreads();
    short8 af[2][3];
    #pragma unroll
    for (int nt = 0; nt < 2; ++nt) {
        int n = wave * 32 + nt * 16 + lr;
        #pragma unroll
        for (int kk = 0; kk < 3; ++kk) {
            int kb = kk * 32 + lg * 8;
            U8 t;
            #pragma unroll
            for (int j = 0; j < 4; ++j) {
                unsigned e0 = xs[kb + 2 * j][n];
                unsigned e1 = xs[kb + 2 * j + 1][n];
                t.u[j] = e0 | (e1 << 16);
            }
            af[nt][kk] = t.s;
        }
    }
    __syncthreads();                              // xs reads complete; safe to overwrite
    const ushort* Wg = W + (size_t)og * 96 * 96 + (size_t)lr * 96 + lg * 8;
    ushort* ys = &xs[0][0];                       // [96][136]
    #pragma unroll
    for (int mt = 0; mt < 6; ++mt) {
        f32x4 a0 = {0.f, 0.f, 0.f, 0.f}, a1 = {0.f, 0.f, 0.f, 0.f};
        #pragma unroll
        for (int kk = 0; kk < 3; ++kk) {
            short8 wf = *(const short8*)(Wg + (size_t)mt * 16 * 96 + kk * 32);
            a0 = mfma16(af[0][kk], wf, a0);
            a1 = mfma16(af[1][kk], wf, a1);
        }
        unsigned* d0 = (unsigned*)&ys[(mt * 16 + lr) * 136 + wave * 32 + lg * 4];
        d0[0] = pk2(a0[0], a0[1]);
        d0[1] = pk2(a0[2], a0[3]);
        unsigned* d1 = (unsigned*)&ys[(mt * 16 + lr) * 136 + wave * 32 + 16 + lg * 4];
        d1[0] = pk2(a1[0], a1[1]);
        d1[1] = pk2(a1[2], a1[3]);
    }
    __syncthreads();
    ushort* Yg = Y + (size_t)(b * 288 + og * 96) * HW + n0;
    int row0 = tid >> 4, g = tid & 15;
    #pragma unroll
    for (int p = 0; p < 6; ++p) {
        int row = p * 16 + row0;
        *(short8*)&Yg[(size_t)row * HW + 8 * g] = *(const short8*)&ys[row * 136 + 8 * g];
    }
}

// ---------------- depthwise 3x3 on V channels only ----------------
__global__ __launch_bounds__(256) void dwv_kernel(const ushort* __restrict__ Y,
                                                  const float* __restrict__ kvdw,
                                                  ushort* __restrict__ V) {
    __shared__ ushort tile[34 * 256];
    int tid = threadIdx.x;
    int cv = blockIdx.y % 96, b = blockIdx.y / 96;
    int r0 = blockIdx.x * 32;
    const float* w = kvdw + (96 + cv) * 9;
    float w00 = w[0], w01 = w[1], w02 = w[2], w10 = w[3], w11 = w[4],
          w12 = w[5], w20 = w[6], w21 = w[7], w22 = w[8];
    const ushort* src = Y + (size_t)(b * 288 + 192 + cv) * HW;
    #pragma unroll
    for (int i = 0; i < 5; ++i) {
        int idx = tid + i * 256;
        if (idx < 34 * 32) {
            int row = idx >> 5, g = idx & 31;
            int gr = r0 - 1 + row;
            short8 v;
            if (gr >= 0 && gr < 256) v = *(const short8*)(src + gr * 256 + 8 * g);
            else v = (short8){0, 0, 0, 0, 0, 0, 0, 0};
            *(short8*)&tile[row * 256 + 8 * g] = v;
        }
    }
    __syncthreads();
    int wave = tid >> 6, lane = tid & 63;
    float rows[3][6];
    #define LOADROW(LROW, D)                                                 \
    {                                                                        \
        ushort4 t4 = *(const ushort4*)&tile[(LROW) * 256 + 4 * lane];        \
        float c0 = bf2f(t4.x), c1 = bf2f(t4.y), c2 = bf2f(t4.z), c3 = bf2f(t4.w); \
        float lft = __shfl(c3, lane - 1);                                    \
        float rgt = __shfl(c0, lane + 1);                                    \
        if (lane == 0) lft = 0.f;                                            \
        if (lane == 63) rgt = 0.f;                                           \
        D[0] = lft; D[1] = c0; D[2] = c1; D[3] = c2; D[4] = c3; D[5] = rgt;  \
    }
    LOADROW(wave * 8 + 0, rows[0]);
    LOADROW(wave * 8 + 1, rows[1]);
    ushort* dst = V + (size_t)(b * 96 + cv) * HW;
    #pragma unroll
    for (int orow = 0; orow < 8; ++orow) {
        LOADROW(wave * 8 + orow + 2, rows[(orow + 2) % 3]);
        float* ra = rows[orow % 3];
        float* rb = rows[(orow + 1) % 3];
        float* rc = rows[(orow + 2) % 3];
        float acc[4];
        #pragma unroll
        for (int j = 0; j < 4; ++j)
            acc[j] = w00 * ra[j] + w01 * ra[j + 1] + w02 * ra[j + 2]
                   + w10 * rb[j] + w11 * rb[j + 1] + w12 * rb[j + 2]
                   + w20 * rc[j] + w21 * rc[j + 1] + w22 * rc[j + 2];
        uint2 pv;
        pv.x = pk2(acc[0], acc[1]);
        pv.y = pk2(acc[2], acc[3]);
        *(uint2*)&dst[(r0 + wave * 8 + orow) * 256 + 4 * lane] = pv;
    }
    #undef LOADROW
}

// ---------------- Gram with fused dw(q),dw(k) + SSQ; 2-row chunks ----------------
__global__ __launch_bounds__(256, 2) void gram_kernel(
        const ushort* __restrict__ Yc, const ushort* __restrict__ Yt,
        const float* __restrict__ qdw_c, const float* __restrict__ qdw_t,
        const float* __restrict__ kvdw_c, const float* __restrict__ kvdw_t,
        float* __restrict__ Gpart, float* __restrict__ SSQ) {
    __shared__ ushort qs[32 * 512];
    __shared__ ushort kss[32 * 512];
    __shared__ float Gp[4][32][32];
    __shared__ float wgt[2][32][9];
    int tid = threadIdx.x, wave = tid >> 6, lane = tid & 63;
    int lr = lane & 15, lg = lane >> 4;
    int code = blockIdx.y;                        // a*6 + b*3 + h
    int a = code / 6, b = (code % 6) / 3, h = code % 3;
    int r0 = blockIdx.x * 2;                      // 2 output rows per block
    const ushort* qsrc = a ? Yt : Yc;
    const ushort* ksrc = a ? Yc : Yt;
    const float* qdw = a ? qdw_t : qdw_c;
    const float* kdw = a ? kvdw_c : kvdw_t;
    for (int idx = tid; idx < 576; idx += 256) {
        int sel = idx >= 288;
        int i = sel ? idx - 288 : idx;
        int ch = i / 9, e = i % 9;
        wgt[sel][ch][e] = sel ? kdw[(32 * h + ch) * 9 + e] : qdw[(32 * h + ch) * 9 + e];
    }
    __syncthreads();
    // ---- dw phase: each thread computes 32 px of one channel ----
    int seg = tid & 15, chl = tid >> 4;
    int row = r0 + (seg >> 3), cs = (seg & 7) * 32;
#define LOAD_ROW(R, F)                                                        \
    {                                                                         \
        int r_ = (R);                                                         \
        if ((unsigned)r_ < 256u) {                                            \
            const ushort* rp = p0 + r_ * 256 + cs;                            \
            U8 u0, u1, u2, u3;                                                \
            u0.s = *(const short8*)(rp);                                      \
            u1.s = *(const short8*)(rp + 8);                                  \
            u2.s = *(const short8*)(rp + 16);                                 \
            u3.s = *(const short8*)(rp + 24);                                 \
            _Pragma("unroll")                                                 \
            for (int j_ = 0; j_ < 8; ++j_) {                                  \
                F[1 + j_] = bf2f(u0.h[j_]);  F[9 + j_] = bf2f(u1.h[j_]);      \
                F[17 + j_] = bf2f(u2.h[j_]); F[25 + j_] = bf2f(u3.h[j_]);     \
            }                                                                 \
            F[0] = cs ? bf2f(rp[-1]) : 0.f;                                   \
            F[33] = (cs < 224) ? bf2f(rp[32]) : 0.f;                          \
        } else {                                                              \
            _Pragma("unroll")                                                 \
            for (int j_ = 0; j_ < 34; ++j_) F[j_] = 0.f;                      \
        }                                                                     \
    }
    for (int pass = 0; pass < 4; ++pass) {
        int sel = pass >> 1, half = pass & 1;
        int ch = half * 16 + chl;
        int gch = sel ? (96 + 32 * h + ch) : (32 * h + ch);
        const ushort* p0 = (sel ? ksrc : qsrc) + (size_t)(b * 288 + gch) * HW;
        const float* w = wgt[sel][ch];
        float w0 = w[0], w1 = w[1], w2 = w[2], w3 = w[3], w4 = w[4],
              w5 = w[5], w6 = w[6], w7 = w[7], w8 = w[8];
        float fa[34], fb[34], acc[32];
        LOAD_ROW(row - 1, fa);
        #pragma unroll
        for (int j = 0; j < 32; ++j)
            acc[j] = w0 * fa[j] + w1 * fa[j + 1] + w2 * fa[j + 2];
        LOAD_ROW(row, fb);
        #pragma unroll
        for (int j = 0; j < 32; ++j)
            acc[j] += w3 * fb[j] + w4 * fb[j + 1] + w5 * fb[j + 2];
        LOAD_ROW(row + 1, fa);
        #pragma unroll
        for (int j = 0; j < 32; ++j)
            acc[j] += w6 * fa[j] + w7 * fa[j + 1] + w8 * fa[j + 2];
        float ssq = 0.f;
        #pragma unroll
        for (int j = 0; j < 32; ++j) ssq += acc[j] * acc[j];
        ssq += __shfl_xor(ssq, 1);
        ssq += __shfl_xor(ssq, 2);
        ssq += __shfl_xor(ssq, 4);
        ssq += __shfl_xor(ssq, 8);
        if (seg == 0)
            atomicAdd(&SSQ[((a * 2 + b) * 2 + sel) * 96 + 32 * h + ch], ssq);
        ushort* dst = sel ? kss : qs;
        #pragma unroll
        for (int g4 = 0; g4 < 4; ++g4) {
            int g = (seg >> 3) * 32 + (seg & 7) * 4 + g4;
            int off = ch * 512 + ((g * 8) ^ ((ch & 7) << 3));
            U8 t;
            t.u[0] = pk2(acc[g4 * 8 + 0], acc[g4 * 8 + 1]);
            t.u[1] = pk2(acc[g4 * 8 + 2], acc[g4 * 8 + 3]);
            t.u[2] = pk2(acc[g4 * 8 + 4], acc[g4 * 8 + 5]);
            t.u[3] = pk2(acc[g4 * 8 + 6], acc[g4 * 8 + 7]);
            *(short8*)&dst[off] = t.s;
        }
    }
#undef LOAD_ROW
    __syncthreads();
    // ---- MFMA phase: 512-px chunk, 16 k-steps split over 4 waves ----
    f32x4 acc2[2][2];
    #pragma unroll
    for (int i = 0; i < 2; ++i)
        #pragma unroll
        for (int j = 0; j < 2; ++j) acc2[i][j] = (f32x4){0.f, 0.f, 0.f, 0.f};
    #pragma unroll
    for (int j = 0; j < 4; ++j) {
        int ks_ = wave * 4 + j;
        int c0 = (ks_ * 32 + lg * 8) ^ ((lr & 7) << 3);
        short8 a0 = *(const short8*)&qs[lr * 512 + c0];
        short8 a1 = *(const short8*)&qs[(16 + lr) * 512 + c0];
        short8 b0 = *(const short8*)&kss[lr * 512 + c0];
        short8 b1 = *(const short8*)&kss[(16 + lr) * 512 + c0];
        acc2[0][0] = mfma16(a0, b0, acc2[0][0]);
        acc2[0][1] = mfma16(a0, b1, acc2[0][1]);
        acc2[1][0] = mfma16(a1, b0, acc2[1][0]);
        acc2[1][1] = mfma16(a1, b1, acc2[1][1]);
    }
    #pragma unroll
    for (int i = 0; i < 2; ++i)
        #pragma unroll
        for (int j = 0; j < 2; ++j)
            #pragma unroll
            for (int r = 0; r < 4; ++r)
                Gp[wave][i * 16 + lg * 4 + r][j * 16 + lr] = acc2[i][j][r];
    __syncthreads();
    float* Gout = Gpart + ((size_t)code * GNS + blockIdx.x) * 1024;
    for (int idx = tid; idx < 1024; idx += 256) {
        float ssum = 0.f;
        #pragma unroll
        for (int wv = 0; wv < 4; ++wv) ssum += (&Gp[wv][0][0])[idx];
        Gout[idx] = ssum;
    }
}

// ---------------- reduce partials + softmax + fold attn into M matrices ----------------
__global__ __launch_bounds__(256) void attn_kernel(const float* __restrict__ Gpart,
                                                   const float* __restrict__ SSQ,
                                                   const float* __restrict__ temperature,
                                                   const float* __restrict__ W1,
                                                   const float* __restrict__ W2,
                                                   ushort* __restrict__ Mcat) {
    __shared__ float Gs[1024];
    __shared__ float nq[32], nk[32], A[32][32];
    int tid = threadIdx.x;
    int code = blockIdx.x;
    int a = code / 6, b = (code % 6) / 3, h = code % 3;
    const float* gp = Gpart + (size_t)code * GNS * 1024;
    #pragma unroll
    for (int j = 0; j < 4; ++j) {
        int idx = tid + j * 256;
        float s = 0.f;
        #pragma unroll 8
        for (int p = 0; p < GNS; ++p) s += gp[(size_t)p * 1024 + idx];
        Gs[idx] = s;
    }
    if (tid < 32)
        nq[tid] = fmaxf(sqrtf(fmaxf(SSQ[((a * 2 + b) * 2 + 0) * 96 + 32 * h + tid], 0.f)), 1e-12f);
    else if (tid < 64)
        nk[tid - 32] = fmaxf(sqrtf(fmaxf(SSQ[((a * 2 + b) * 2 + 1) * 96 + 32 * h + (tid - 32)], 0.f)), 1e-12f);
    __syncthreads();
    if (tid < 32) {
        float t = temperature[h];
        float lgv[32];
        float inq = t / nq[tid];
        float mx = -1e30f;
        #pragma unroll
        for (int j = 0; j < 32; ++j) { lgv[j] = Gs[tid * 32 + j] * inq / nk[j]; mx = fmaxf(mx, lgv[j]); }
        float ssum = 0.f;
        #pragma unroll
        for (int j = 0; j < 32; ++j) { lgv[j] = expf(lgv[j] - mx); ssum += lgv[j]; }
        float inv = 1.f / ssum;
        #pragma unroll
        for (int j = 0; j < 32; ++j) A[tid][j] = lgv[j] * inv;
    }
    __syncthreads();
    const float* Wm = (a == 0) ? W1 : W2;
    for (int idx = tid; idx < 96 * 32; idx += 256) {
        int o = idx >> 5, d = idx & 31;
        float acc = 0.f;
        #pragma unroll
        for (int i = 0; i < 32; ++i)
            acc += Wm[o * 96 + 32 * h + i] * A[i][d];
        Mcat[(size_t)(b * 96 + o) * 192 + a * 96 + 32 * h + d] = f2bf(acc);
    }
}

// ---------------- final: out = [M1 M2].[v_t ; v_c] + bias ----------------
__global__ __launch_bounds__(256, 2) void final_kernel(const ushort* __restrict__ Vc,
                                                       const ushort* __restrict__ Vt,
                                                       const ushort* __restrict__ Mcat,
                                                       const float* __restrict__ bias,
                                                       float* __restrict__ out) {
    __shared__ float smem[96 * 132];              // ushort[192][132] staging, then float[96][132]
    ushort* vs = (ushort*)smem;
    int tid = threadIdx.x;
    int n0 = blockIdx.x * 128, b = blockIdx.y;
    int wave = tid >> 6, lane = tid & 63, lr = lane & 15, lg = lane >> 4;
    #pragma unroll
    for (int i = 0; i < 12; ++i) {
        int idx = tid + i * 256;                  // 3072 = 192 d x 16 granules
        int d = idx >> 4, g = idx & 15;
        const ushort* sp = (d < 96) ? (Vt + (size_t)(b * 96 + d) * HW)
                                    : (Vc + (size_t)(b * 96 + d - 96) * HW);
        U8 t;
        t.s = *(const short8*)(sp + n0 + 8 * g);
        unsigned* dst = (unsigned*)&vs[d * 132 + 8 * g];
        dst[0] = t.u[0]; dst[1] = t.u[1]; dst[2] = t.u[2]; dst[3] = t.u[3];
    }
    __syncthreads();
    short8 vf[2][6];
    #pragma unroll
    for (int nt = 0; nt < 2; ++nt) {
        int n = wave * 32 + nt * 16 + lr;
        #pragma unroll
        for (int kk = 0; kk < 6; ++kk) {
            int kb = kk * 32 + lg * 8;
            U8 t;
            #pragma unroll
            for (int j = 0; j < 4; ++j) {
                unsigned e0 = vs[(kb + 2 * j) * 132 + n];
                unsigned e1 = vs[(kb + 2 * j + 1) * 132 + n];
                t.u[j] = e0 | (e1 << 16);
            }
            vf[nt][kk] = t.s;
        }
    }
    __syncthreads();
    const ushort* Mb = Mcat + (size_t)b * 96 * 192;
    #pragma unroll
    for (int mt = 0; mt < 6; ++mt) {
        f32x4 a0 = {0.f, 0.f, 0.f, 0.f}, a1 = {0.f, 0.f, 0.f, 0.f};
        #pragma unroll
        for (int kk = 0; kk < 6; ++kk) {
            short8 mf = *(const short8*)&Mb[(size_t)(mt * 16 + lr) * 192 + kk * 32 + lg * 8];
            a0 = mfma16(vf[0][kk], mf, a0);
            a1 = mfma16(vf[1][kk], mf, a1);
        }
        *(float4*)&smem[(mt * 16 + lr) * 132 + wave * 32 + lg * 4] =
            make_float4(a0[0], a0[1], a0[2], a0[3]);
        *(float4*)&smem[(mt * 16 + lr) * 132 + wave * 32 + 16 + lg * 4] =
            make_float4(a1[0], a1[1], a1[2], a1[3]);
    }
    __syncthreads();
    float* outb = out + (size_t)b * 96 * HW + n0;
    int row0 = tid >> 5, q = tid & 31;
    #pragma unroll
    for (int p = 0; p < 12; ++p) {
        int row = p * 8 + row0;
        float4 v = *(const float4*)&smem[row * 132 + 4 * q];
        float bb = bias[row];
        v.x += bb; v.y += bb; v.z += bb; v.w += bb;
        *(float4*)&outb[(size_t)row * HW + 4 * q] = v;
    }
}

extern "C" void kernel_launch(void* const* d_in, const int* in_sizes, int n_in,
                              void* d_out, int out_size, void* d_ws, size_t ws_size,
                              hipStream_t stream) {
    const float* low    = (const float*)d_in[0];
    const float* high   = (const float*)d_in[1];
    const float* temp   = (const float*)d_in[2];
    const float* qc_w   = (const float*)d_in[3];
    const float* qdw_c  = (const float*)d_in[4];
    const float* kvc_w  = (const float*)d_in[5];
    const float* kvdw_c = (const float*)d_in[6];
    const float* qt_w   = (const float*)d_in[7];
    const float* qdw_t  = (const float*)d_in[8];
    const float* kvt_w  = (const float*)d_in[9];
    const float* kvdw_t = (const float*)d_in[10];
    const float* po_c   = (const float*)d_in[11];
    const float* po_t   = (const float*)d_in[12];
    const float* cw     = (const float*)d_in[13];
    const float* cb     = (const float*)d_in[14];
    float* out = (float*)d_out;

    char* ws = (char*)d_ws;
    const size_t SY = (size_t)2 * 288 * HW * 2;   // 75,497,472 B
    const size_t SV = (size_t)2 * 96 * HW * 2;    // 25,165,824 B
    ushort* Yc = (ushort*)(ws);
    ushort* Yt = (ushort*)(ws + SY);
    ushort* Vc = (ushort*)(ws + 2 * SY);
    ushort* Vt = (ushort*)(ws + 2 * SY + SV);
    float* Gpart = (float*)(ws + 2 * SY + 2 * SV); // 12*128*1024*4 = 6.3 MB (fits in slot2 tail)
    char* p = ws + 3 * SY;
    ushort* Wc = (ushort*)p; p += 288 * 96 * 2;
    ushort* Wt = (ushort*)p; p += 288 * 96 * 2;
    float* W1  = (float*)p;  p += 96 * 96 * 4;
    float* W2  = (float*)p;  p += 96 * 96 * 4;
    float* SSQ = (float*)p;  p += 8 * 96 * 4;
    ushort* Mcat = (ushort*)p; p += 2 * 96 * 192 * 2;
    if ((size_t)(p - ws) > ws_size) return;

    prep_kernel<<<81, 256, 0, stream>>>(qc_w, kvc_w, qt_w, kvt_w, cw, po_c, po_t, Wc, Wt, W1, W2, SSQ);
    conv_kernel<<<dim3(512, 3, 2), 256, 0, stream>>>(high, Wc, Yc);
    conv_kernel<<<dim3(512, 3, 2), 256, 0, stream>>>(low, Wt, Yt);
    gram_kernel<<<dim3(GNS, 12), 256, 0, stream>>>(Yc, Yt, qdw_c, qdw_t, kvdw_c, kvdw_t, Gpart, SSQ);
    dwv_kernel<<<dim3(8, 192), 256, 0, stream>>>(Yc, kvdw_c, Vc);
    dwv_kernel<<<dim3(8, 192), 256, 0, stream>>>(Yt, kvdw_t, Vt);
    attn_kernel<<<12, 256, 0, stream>>>(Gpart, SSQ, temp, W1, W2, Mcat);
    final_kernel<<<dim3(512, 2), 256, 0, stream>>>(Vc, Vt, Mcat, cb, out);
}

// Round 9
// 239.724 us; speedup vs baseline: 1.2109x; 1.2109x over previous
//
#include <hip/hip_runtime.h>
#include <hip/hip_bf16.h>

#define HW 65536
#define GNS 64

typedef __attribute__((ext_vector_type(8))) short short8;
typedef __attribute__((ext_vector_type(4))) float f32x4;
union U8 { short8 s; unsigned u[4]; ushort h[8]; };

static __device__ __forceinline__ ushort f2bf(float f) {
    union { float f; unsigned u; } v; v.f = f;
    unsigned u = v.u;
    unsigned r = (u + 0x7fffu + ((u >> 16) & 1u)) >> 16;
    return (ushort)r;
}
static __device__ __forceinline__ float bf2f(ushort u) {
    union { unsigned u; float f; } v; v.u = ((unsigned)u) << 16; return v.f;
}
static __device__ __forceinline__ unsigned pk2(float a, float b) {
    __hip_bfloat162 h = __float22bfloat162_rn(make_float2(a, b));
    union { __hip_bfloat162 h; unsigned u; } c; c.h = h; return c.u;
}
static __device__ __forceinline__ f32x4 mfma16(short8 a, short8 b, f32x4 c) {
    return __builtin_amdgcn_mfma_f32_16x16x32_bf16(a, b, c, 0, 0, 0);
}

// ---------------- prep: pack conv weights bf16; fold W1/W2; zero SSQ ----------------
__global__ __launch_bounds__(256) void prep_kernel(
        const float* __restrict__ qc, const float* __restrict__ kvc,
        const float* __restrict__ qt, const float* __restrict__ kvt,
        const float* __restrict__ cw, const float* __restrict__ poc, const float* __restrict__ pot,
        ushort* __restrict__ Wc, ushort* __restrict__ Wt,
        float* __restrict__ W1, float* __restrict__ W2, float* __restrict__ SSQ) {
    int bx = blockIdx.x, tid = threadIdx.x;
    if (bx < 9) {
        for (int idx = bx * 256 + tid; idx < 288 * 96; idx += 9 * 256) {
            Wc[idx] = f2bf(idx < 96 * 96 ? qc[idx] : kvc[idx - 96 * 96]);
            Wt[idx] = f2bf(idx < 96 * 96 ? qt[idx] : kvt[idx - 96 * 96]);
        }
        if (bx == 0)
            for (int idx = tid; idx < 8 * 96; idx += 256) SSQ[idx] = 0.f;
    } else {
        int idx = (bx - 9) * 256 + tid;          // 0..18431
        int sel = idx < 9216 ? 0 : 1;
        int i = sel ? idx - 9216 : idx;
        int o = i / 96, m = i % 96;
        const float* po = sel ? pot : poc;
        float acc = 0.f;
        for (int p = 0; p < 96; ++p)
            acc += cw[o * 192 + sel * 96 + p] * po[p * 96 + m];
        (sel ? W2 : W1)[i] = acc;
    }
}

// ---------------- conv1x1: stage X once; all 288 o in 3 restage chunks ----------------
__global__ __launch_bounds__(256, 2) void conv_kernel(const float* __restrict__ X,
                                                      const ushort* __restrict__ W,
                                                      ushort* __restrict__ Y) {
    __shared__ ushort xs[96][136];                // X staging, reused as output restage
    int tid = threadIdx.x;
    int n0 = blockIdx.x * 128;
    int b = blockIdx.y;
    int wave = tid >> 6, lane = tid & 63, lr = lane & 15, lg = lane >> 4;
    // 1) stage X tile (fp32 -> bf16), read X exactly once per (b, n-tile)
    const float* Xb = X + (size_t)b * 96 * HW + n0;
    #pragma unroll
    for (int i = 0; i < 12; ++i) {
        int idx = tid + i * 256;                  // 3072 = 96 ch x 32 quads
        int ch = idx >> 5, g = idx & 31;
        float4 v = *(const float4*)(Xb + (size_t)ch * HW + 4 * g);
        unsigned* d = (unsigned*)&xs[ch][4 * g];
        d[0] = pk2(v.x, v.y);
        d[1] = pk2(v.z, v.w);
    }
    __syncthreads();
    // 2) build X fragments (held in registers for all 3 chunks)
    short8 af[2][3];
    #pragma unroll
    for (int nt = 0; nt < 2; ++nt) {
        int n = wave * 32 + nt * 16 + lr;
        #pragma unroll
        for (int kk = 0; kk < 3; ++kk) {
            int kb = kk * 32 + lg * 8;
            U8 t;
            #pragma unroll
            for (int j = 0; j < 4; ++j) {
                unsigned e0 = xs[kb + 2 * j][n];
                unsigned e1 = xs[kb + 2 * j + 1][n];
                t.u[j] = e0 | (e1 << 16);
            }
            af[nt][kk] = t.s;
        }
    }
    __syncthreads();                              // xs reads complete; safe to overwrite
    ushort* ys = &xs[0][0];                       // [96][136] restage buffer
    int row0 = tid >> 4, g = tid & 15;
    for (int og = 0; og < 3; ++og) {
        // 3) MFMA + restage 96 o-rows into LDS (n-contiguous per o-row)
        const ushort* Wg = W + (size_t)og * 96 * 96 + (size_t)lr * 96 + lg * 8;
        #pragma unroll
        for (int mt = 0; mt < 6; ++mt) {
            f32x4 a0 = {0.f, 0.f, 0.f, 0.f}, a1 = {0.f, 0.f, 0.f, 0.f};
            #pragma unroll
            for (int kk = 0; kk < 3; ++kk) {
                short8 wf = *(const short8*)(Wg + (size_t)mt * 16 * 96 + kk * 32);
                a0 = mfma16(af[0][kk], wf, a0);
                a1 = mfma16(af[1][kk], wf, a1);
            }
            unsigned* d0 = (unsigned*)&ys[(mt * 16 + lr) * 136 + wave * 32 + lg * 4];
            d0[0] = pk2(a0[0], a0[1]);
            d0[1] = pk2(a0[2], a0[3]);
            unsigned* d1 = (unsigned*)&ys[(mt * 16 + lr) * 136 + wave * 32 + 16 + lg * 4];
            d1[0] = pk2(a1[0], a1[1]);
            d1[1] = pk2(a1[2], a1[3]);
        }
        __syncthreads();
        // 4) cooperative contiguous stores: 256B per o-row
        ushort* Yg = Y + (size_t)(b * 288 + og * 96) * HW + n0;
        #pragma unroll
        for (int p = 0; p < 6; ++p) {
            int row = p * 16 + row0;
            *(short8*)&Yg[(size_t)row * HW + 8 * g] = *(const short8*)&ys[row * 136 + 8 * g];
        }
        __syncthreads();
    }
}

// ---------------- depthwise 3x3 SAME + per-channel sum-of-squares ----------------
__global__ __launch_bounds__(256) void dw_kernel(const ushort* __restrict__ Y,
                                                 const float* __restrict__ qdw,
                                                 const float* __restrict__ kvdw,
                                                 ushort* __restrict__ QKV,
                                                 float* __restrict__ SSQ, int is_c) {
    __shared__ ushort tile[34 * 256];
    int tid = threadIdx.x;
    int ch = blockIdx.y % 288, b = blockIdx.y / 288;
    int r0 = blockIdx.x * 32;
    const float* w = (ch < 96) ? (qdw + ch * 9) : (kvdw + (ch - 96) * 9);
    float w00 = w[0], w01 = w[1], w02 = w[2], w10 = w[3], w11 = w[4],
          w12 = w[5], w20 = w[6], w21 = w[7], w22 = w[8];
    const ushort* src = Y + (size_t)(b * 288 + ch) * HW;
    #pragma unroll
    for (int i = 0; i < 5; ++i) {
        int idx = tid + i * 256;
        if (idx < 34 * 32) {
            int row = idx >> 5, g = idx & 31;
            int gr = r0 - 1 + row;
            short8 v;
            if (gr >= 0 && gr < 256) v = *(const short8*)(src + gr * 256 + 8 * g);
            else v = (short8){0, 0, 0, 0, 0, 0, 0, 0};
            *(short8*)&tile[row * 256 + 8 * g] = v;
        }
    }
    __syncthreads();
    int wave = tid >> 6, lane = tid & 63;
    float rows[3][6];
    float ssq = 0.f;
    #define LOADROW(LROW, D)                                                 \
    {                                                                        \
        ushort4 t4 = *(const ushort4*)&tile[(LROW) * 256 + 4 * lane];        \
        float c0 = bf2f(t4.x), c1 = bf2f(t4.y), c2 = bf2f(t4.z), c3 = bf2f(t4.w); \
        float lft = __shfl(c3, lane - 1);                                    \
        float rgt = __shfl(c0, lane + 1);                                    \
        if (lane == 0) lft = 0.f;                                            \
        if (lane == 63) rgt = 0.f;                                           \
        D[0] = lft; D[1] = c0; D[2] = c1; D[3] = c2; D[4] = c3; D[5] = rgt;  \
    }
    LOADROW(wave * 8 + 0, rows[0]);
    LOADROW(wave * 8 + 1, rows[1]);
    ushort* dst = QKV + (size_t)(b * 288 + ch) * HW;
    #pragma unroll
    for (int orow = 0; orow < 8; ++orow) {
        LOADROW(wave * 8 + orow + 2, rows[(orow + 2) % 3]);
        float* ra = rows[orow % 3];
        float* rb = rows[(orow + 1) % 3];
        float* rc = rows[(orow + 2) % 3];
        float acc[4];
        #pragma unroll
        for (int j = 0; j < 4; ++j) {
            acc[j] = w00 * ra[j] + w01 * ra[j + 1] + w02 * ra[j + 2]
                   + w10 * rb[j] + w11 * rb[j + 1] + w12 * rb[j + 2]
                   + w20 * rc[j] + w21 * rc[j + 1] + w22 * rc[j + 2];
            ssq += acc[j] * acc[j];
        }
        uint2 pv;
        pv.x = pk2(acc[0], acc[1]);
        pv.y = pk2(acc[2], acc[3]);
        *(uint2*)&dst[(r0 + wave * 8 + orow) * 256 + 4 * lane] = pv;
    }
    #undef LOADROW
    if (ch < 192) {
        #pragma unroll
        for (int off = 1; off < 64; off <<= 1) ssq += __shfl_xor(ssq, off);
        if (lane == 0) {
            int t_ = ch >= 96;
            int chq = t_ ? ch - 96 : ch;
            int a_ = is_c ? t_ : (1 - t_);
            atomicAdd(&SSQ[((a_ * 2 + b) * 2 + t_) * 96 + chq], ssq);
        }
    }
}

// ---------------- Gram: LDS-staged, XOR-swizzled, partials to Gpart ----------------
__global__ __launch_bounds__(256) void gram_kernel(const ushort* __restrict__ QKVc,
                                                   const ushort* __restrict__ QKVt,
                                                   float* __restrict__ Gpart) {
    __shared__ ushort qs[32 * 256];
    __shared__ ushort ks2[32 * 256];
    __shared__ float Gp[4][32][32];
    int tid = threadIdx.x, wave = tid >> 6, lane = tid & 63;
    int lr = lane & 15, lg = lane >> 4;
    int code = blockIdx.y;                        // a*6 + b*3 + h
    int a = code / 6, b = (code % 6) / 3, h = code % 3;
    const ushort* qsrc = (a == 0) ? QKVc : QKVt;
    const ushort* ksrc = (a == 0) ? QKVt : QKVc;
    const ushort* qb = qsrc + (size_t)(b * 288 + 32 * h) * HW + blockIdx.x * 1024;
    const ushort* kb = ksrc + (size_t)(b * 288 + 96 + 32 * h) * HW + blockIdx.x * 1024;
    f32x4 acc[2][2];
    #pragma unroll
    for (int i = 0; i < 2; ++i)
        #pragma unroll
        for (int j = 0; j < 2; ++j) acc[i][j] = (f32x4){0.f, 0.f, 0.f, 0.f};
    for (int ph = 0; ph < 4; ++ph) {
        int noff = ph * 256;
        #pragma unroll
        for (int i = 0; i < 4; ++i) {
            int idx = tid + i * 256;
            int row = idx >> 5, g = idx & 31;
            int col = (g * 8) ^ ((row & 7) << 3);
            *(short8*)&qs[row * 256 + col] = *(const short8*)(qb + (size_t)row * HW + noff + 8 * g);
            *(short8*)&ks2[row * 256 + col] = *(const short8*)(kb + (size_t)row * HW + noff + 8 * g);
        }
        __syncthreads();
        #pragma unroll
        for (int j = 0; j < 2; ++j) {
            int ks_ = wave * 2 + j;
            int c0 = (ks_ * 32 + lg * 8) ^ ((lr & 7) << 3);
            short8 a0 = *(const short8*)&qs[lr * 256 + c0];
            short8 a1 = *(const short8*)&qs[(16 + lr) * 256 + c0];
            short8 b0 = *(const short8*)&ks2[lr * 256 + c0];
            short8 b1 = *(const short8*)&ks2[(16 + lr) * 256 + c0];
            acc[0][0] = mfma16(a0, b0, acc[0][0]);
            acc[0][1] = mfma16(a0, b1, acc[0][1]);
            acc[1][0] = mfma16(a1, b0, acc[1][0]);
            acc[1][1] = mfma16(a1, b1, acc[1][1]);
        }
        __syncthreads();
    }
    #pragma unroll
    for (int i = 0; i < 2; ++i)
        #pragma unroll
        for (int j = 0; j < 2; ++j)
            #pragma unroll
            for (int r = 0; r < 4; ++r)
                Gp[wave][i * 16 + lg * 4 + r][j * 16 + lr] = acc[i][j][r];
    __syncthreads();
    float* Gout = Gpart + ((size_t)code * GNS + blockIdx.x) * 1024;
    for (int idx = tid; idx < 1024; idx += 256) {
        float ssum = 0.f;
        #pragma unroll
        for (int wv = 0; wv < 4; ++wv) ssum += (&Gp[wv][0][0])[idx];
        Gout[idx] = ssum;
    }
}

// ---------------- reduce partials + softmax + fold attn into M matrices ----------------
__global__ __launch_bounds__(256) void attn_kernel(const float* __restrict__ Gpart,
                                                   const float* __restrict__ SSQ,
                                                   const float* __restrict__ temperature,
                                                   const float* __restrict__ W1,
                                                   const float* __restrict__ W2,
                                                   ushort* __restrict__ Mcat) {
    __shared__ float Gs[1024];
    __shared__ float nq[32], nk[32], A[32][32];
    int tid = threadIdx.x;
    int code = blockIdx.x;
    int a = code / 6, b = (code % 6) / 3, h = code % 3;
    const float* gp = Gpart + (size_t)code * GNS * 1024;
    #pragma unroll
    for (int j = 0; j < 4; ++j) {
        int idx = tid + j * 256;
        float s = 0.f;
        #pragma unroll 8
        for (int p = 0; p < GNS; ++p) s += gp[(size_t)p * 1024 + idx];
        Gs[idx] = s;
    }
    if (tid < 32)
        nq[tid] = fmaxf(sqrtf(fmaxf(SSQ[((a * 2 + b) * 2 + 0) * 96 + 32 * h + tid], 0.f)), 1e-12f);
    else if (tid < 64)
        nk[tid - 32] = fmaxf(sqrtf(fmaxf(SSQ[((a * 2 + b) * 2 + 1) * 96 + 32 * h + (tid - 32)], 0.f)), 1e-12f);
    __syncthreads();
    if (tid < 32) {
        float t = temperature[h];
        float lgv[32];
        float inq = t / nq[tid];
        float mx = -1e30f;
        #pragma unroll
        for (int j = 0; j < 32; ++j) { lgv[j] = Gs[tid * 32 + j] * inq / nk[j]; mx = fmaxf(mx, lgv[j]); }
        float ssum = 0.f;
        #pragma unroll
        for (int j = 0; j < 32; ++j) { lgv[j] = expf(lgv[j] - mx); ssum += lgv[j]; }
        float inv = 1.f / ssum;
        #pragma unroll
        for (int j = 0; j < 32; ++j) A[tid][j] = lgv[j] * inv;
    }
    __syncthreads();
    const float* Wm = (a == 0) ? W1 : W2;
    for (int idx = tid; idx < 96 * 32; idx += 256) {
        int o = idx >> 5, d = idx & 31;
        float acc = 0.f;
        #pragma unroll
        for (int i = 0; i < 32; ++i)
            acc += Wm[o * 96 + 32 * h + i] * A[i][d];
        Mcat[(size_t)(b * 96 + o) * 192 + a * 96 + 32 * h + d] = f2bf(acc);
    }
}

// ---------------- final: MFMA -> fp32 LDS restage -> 512B/row contiguous stores ----------------
__global__ __launch_bounds__(256, 2) void final_kernel(const ushort* __restrict__ QKVc,
                                                       const ushort* __restrict__ QKVt,
                                                       const ushort* __restrict__ Mcat,
                                                       const float* __restrict__ bias,
                                                       float* __restrict__ out) {
    __shared__ float smem[96 * 132];              // ushort[192][132] staging, then float[96][132]
    ushort* vs = (ushort*)smem;                   // stride 132 ushorts
    int tid = threadIdx.x;
    int n0 = blockIdx.x * 128, b = blockIdx.y;
    int wave = tid >> 6, lane = tid & 63, lr = lane & 15, lg = lane >> 4;
    #pragma unroll
    for (int i = 0; i < 12; ++i) {
        int idx = tid + i * 256;                  // 3072 = 192 d x 16 granules
        int d = idx >> 4, g = idx & 15;
        const ushort* sp = (d < 96) ? (QKVt + (size_t)(b * 288 + 192 + d) * HW)
                                    : (QKVc + (size_t)(b * 288 + 192 + (d - 96)) * HW);
        U8 t;
        t.s = *(const short8*)(sp + n0 + 8 * g);
        unsigned* dst = (unsigned*)&vs[d * 132 + 8 * g];
        dst[0] = t.u[0]; dst[1] = t.u[1]; dst[2] = t.u[2]; dst[3] = t.u[3];
    }
    __syncthreads();
    short8 vf[2][6];
    #pragma unroll
    for (int nt = 0; nt < 2; ++nt) {
        int n = wave * 32 + nt * 16 + lr;
        #pragma unroll
        for (int kk = 0; kk < 6; ++kk) {
            int kb = kk * 32 + lg * 8;
            U8 t;
            #pragma unroll
            for (int j = 0; j < 4; ++j) {
                unsigned e0 = vs[(kb + 2 * j) * 132 + n];
                unsigned e1 = vs[(kb + 2 * j + 1) * 132 + n];
                t.u[j] = e0 | (e1 << 16);
            }
            vf[nt][kk] = t.s;
        }
    }
    __syncthreads();                              // vs reads complete; safe to overwrite
    const ushort* Mb = Mcat + (size_t)b * 96 * 192;
    #pragma unroll
    for (int mt = 0; mt < 6; ++mt) {
        f32x4 a0 = {0.f, 0.f, 0.f, 0.f}, a1 = {0.f, 0.f, 0.f, 0.f};
        #pragma unroll
        for (int kk = 0; kk < 6; ++kk) {
            short8 mf = *(const short8*)&Mb[(size_t)(mt * 16 + lr) * 192 + kk * 32 + lg * 8];
            a0 = mfma16(vf[0][kk], mf, a0);
            a1 = mfma16(vf[1][kk], mf, a1);
        }
        *(float4*)&smem[(mt * 16 + lr) * 132 + wave * 32 + lg * 4] =
            make_float4(a0[0], a0[1], a0[2], a0[3]);
        *(float4*)&smem[(mt * 16 + lr) * 132 + wave * 32 + 16 + lg * 4] =
            make_float4(a1[0], a1[1], a1[2], a1[3]);
    }
    __syncthreads();
    float* outb = out + (size_t)b * 96 * HW + n0;
    int row0 = tid >> 5, q = tid & 31;
    #pragma unroll
    for (int p = 0; p < 12; ++p) {
        int row = p * 8 + row0;
        float4 v = *(const float4*)&smem[row * 132 + 4 * q];
        float bb = bias[row];
        v.x += bb; v.y += bb; v.z += bb; v.w += bb;
        *(float4*)&outb[(size_t)row * HW + 4 * q] = v;
    }
}

extern "C" void kernel_launch(void* const* d_in, const int* in_sizes, int n_in,
                              void* d_out, int out_size, void* d_ws, size_t ws_size,
                              hipStream_t stream) {
    const float* low    = (const float*)d_in[0];
    const float* high   = (const float*)d_in[1];
    const float* temp   = (const float*)d_in[2];
    const float* qc_w   = (const float*)d_in[3];
    const float* qdw_c  = (const float*)d_in[4];
    const float* kvc_w  = (const float*)d_in[5];
    const float* kvdw_c = (const float*)d_in[6];
    const float* qt_w   = (const float*)d_in[7];
    const float* qdw_t  = (const float*)d_in[8];
    const float* kvt_w  = (const float*)d_in[9];
    const float* kvdw_t = (const float*)d_in[10];
    const float* po_c   = (const float*)d_in[11];
    const float* po_t   = (const float*)d_in[12];
    const float* cw     = (const float*)d_in[13];
    const float* cb     = (const float*)d_in[14];
    float* out = (float*)d_out;

    char* ws = (char*)d_ws;
    const size_t SY = (size_t)2 * 288 * HW * 2;   // 75,497,472 B per big tensor
    ushort* Y    = (ushort*)(ws);
    ushort* QKVc = (ushort*)(ws + SY);
    ushort* QKVt = (ushort*)(ws + 2 * SY);
    float* Gpart = (float*)ws;                    // reuses Y (dead after dw_t)
    char* p = ws + 3 * SY;
    ushort* Wc = (ushort*)p; p += 288 * 96 * 2;
    ushort* Wt = (ushort*)p; p += 288 * 96 * 2;
    float* W1  = (float*)p;  p += 96 * 96 * 4;
    float* W2  = (float*)p;  p += 96 * 96 * 4;
    float* SSQ = (float*)p;  p += 8 * 96 * 4;
    ushort* Mcat = (ushort*)p; p += 2 * 96 * 192 * 2;
    if ((size_t)(p - ws) > ws_size) return;

    prep_kernel<<<81, 256, 0, stream>>>(qc_w, kvc_w, qt_w, kvt_w, cw, po_c, po_t, Wc, Wt, W1, W2, SSQ);
    // stream c from high
    conv_kernel<<<dim3(512, 2), 256, 0, stream>>>(high, Wc, Y);
    dw_kernel<<<dim3(8, 576), 256, 0, stream>>>(Y, qdw_c, kvdw_c, QKVc, SSQ, 1);
    // stream t from low
    conv_kernel<<<dim3(512, 2), 256, 0, stream>>>(low, Wt, Y);
    dw_kernel<<<dim3(8, 576), 256, 0, stream>>>(Y, qdw_t, kvdw_t, QKVt, SSQ, 0);
    gram_kernel<<<dim3(GNS, 12), 256, 0, stream>>>(QKVc, QKVt, Gpart);
    attn_kernel<<<12, 256, 0, stream>>>(Gpart, SSQ, temp, W1, W2, Mcat);
    final_kernel<<<dim3(512, 2), 256, 0, stream>>>(QKVc, QKVt, Mcat, cb, out);
}

// Round 10
// 234.962 us; speedup vs baseline: 1.2355x; 1.0203x over previous
//
#include <hip/hip_runtime.h>
#include <hip/hip_bf16.h>

#define HW 65536
#define GNS 64

typedef __attribute__((ext_vector_type(8))) short short8;
typedef __attribute__((ext_vector_type(4))) float f32x4;
union U8 { short8 s; unsigned u[4]; ushort h[8]; };

static __device__ __forceinline__ ushort f2bf(float f) {
    union { float f; unsigned u; } v; v.f = f;
    unsigned u = v.u;
    unsigned r = (u + 0x7fffu + ((u >> 16) & 1u)) >> 16;
    return (ushort)r;
}
static __device__ __forceinline__ float bf2f(ushort u) {
    union { unsigned u; float f; } v; v.u = ((unsigned)u) << 16; return v.f;
}
static __device__ __forceinline__ unsigned pk2(float a, float b) {
    __hip_bfloat162 h = __float22bfloat162_rn(make_float2(a, b));
    union { __hip_bfloat162 h; unsigned u; } c; c.h = h; return c.u;
}
static __device__ __forceinline__ f32x4 mfma16(short8 a, short8 b, f32x4 c) {
    return __builtin_amdgcn_mfma_f32_16x16x32_bf16(a, b, c, 0, 0, 0);
}

// ---------------- prep: pack conv weights bf16; fold W1/W2; zero SSQ ----------------
__global__ __launch_bounds__(256) void prep_kernel(
        const float* __restrict__ qc, const float* __restrict__ kvc,
        const float* __restrict__ qt, const float* __restrict__ kvt,
        const float* __restrict__ cw, const float* __restrict__ poc, const float* __restrict__ pot,
        ushort* __restrict__ Wc, ushort* __restrict__ Wt,
        float* __restrict__ W1, float* __restrict__ W2, float* __restrict__ SSQ) {
    int bx = blockIdx.x, tid = threadIdx.x;
    if (bx < 9) {
        for (int idx = bx * 256 + tid; idx < 288 * 96; idx += 9 * 256) {
            Wc[idx] = f2bf(idx < 96 * 96 ? qc[idx] : kvc[idx - 96 * 96]);
            Wt[idx] = f2bf(idx < 96 * 96 ? qt[idx] : kvt[idx - 96 * 96]);
        }
        if (bx == 0)
            for (int idx = tid; idx < 8 * 96; idx += 256) SSQ[idx] = 0.f;
    } else {
        int idx = (bx - 9) * 256 + tid;          // 0..18431
        int sel = idx < 9216 ? 0 : 1;
        int i = sel ? idx - 9216 : idx;
        int o = i / 96, m = i % 96;
        const float* po = sel ? pot : poc;
        float acc = 0.f;
        for (int p = 0; p < 96; ++p)
            acc += cw[o * 192 + sel * 96 + p] * po[p * 96 + m];
        (sel ? W2 : W1)[i] = acc;
    }
}

// ---------------- conv1x1 (both streams via blockIdx.z) ----------------
__global__ __launch_bounds__(256, 2) void conv_kernel(
        const float* __restrict__ Xc, const float* __restrict__ Xt,
        const ushort* __restrict__ Wcp, const ushort* __restrict__ Wtp,
        ushort* __restrict__ Yco, ushort* __restrict__ Yto) {
    __shared__ ushort xs[96][136];                // X staging, reused as output restage
    int strm = blockIdx.z;
    const float* X = strm ? Xt : Xc;
    const ushort* W = strm ? Wtp : Wcp;
    ushort* Y = strm ? Yto : Yco;
    int tid = threadIdx.x;
    int n0 = blockIdx.x * 128;
    int b = blockIdx.y;
    int wave = tid >> 6, lane = tid & 63, lr = lane & 15, lg = lane >> 4;
    const float* Xb = X + (size_t)b * 96 * HW + n0;
    #pragma unroll
    for (int i = 0; i < 12; ++i) {
        int idx = tid + i * 256;                  // 3072 = 96 ch x 32 quads
        int ch = idx >> 5, g = idx & 31;
        float4 v = *(const float4*)(Xb + (size_t)ch * HW + 4 * g);
        unsigned* d = (unsigned*)&xs[ch][4 * g];
        d[0] = pk2(v.x, v.y);
        d[1] = pk2(v.z, v.w);
    }
    __syncthreads();
    short8 af[2][3];
    #pragma unroll
    for (int nt = 0; nt < 2; ++nt) {
        int n = wave * 32 + nt * 16 + lr;
        #pragma unroll
        for (int kk = 0; kk < 3; ++kk) {
            int kb = kk * 32 + lg * 8;
            U8 t;
            #pragma unroll
            for (int j = 0; j < 4; ++j) {
                unsigned e0 = xs[kb + 2 * j][n];
                unsigned e1 = xs[kb + 2 * j + 1][n];
                t.u[j] = e0 | (e1 << 16);
            }
            af[nt][kk] = t.s;
        }
    }
    __syncthreads();                              // xs reads complete; safe to overwrite
    ushort* ys = &xs[0][0];                       // [96][136] restage buffer
    int row0 = tid >> 4, g = tid & 15;
    for (int og = 0; og < 3; ++og) {
        const ushort* Wg = W + (size_t)og * 96 * 96 + (size_t)lr * 96 + lg * 8;
        #pragma unroll
        for (int mt = 0; mt < 6; ++mt) {
            f32x4 a0 = {0.f, 0.f, 0.f, 0.f}, a1 = {0.f, 0.f, 0.f, 0.f};
            #pragma unroll
            for (int kk = 0; kk < 3; ++kk) {
                short8 wf = *(const short8*)(Wg + (size_t)mt * 16 * 96 + kk * 32);
                a0 = mfma16(af[0][kk], wf, a0);
                a1 = mfma16(af[1][kk], wf, a1);
            }
            unsigned* d0 = (unsigned*)&ys[(mt * 16 + lr) * 136 + wave * 32 + lg * 4];
            d0[0] = pk2(a0[0], a0[1]);
            d0[1] = pk2(a0[2], a0[3]);
            unsigned* d1 = (unsigned*)&ys[(mt * 16 + lr) * 136 + wave * 32 + 16 + lg * 4];
            d1[0] = pk2(a1[0], a1[1]);
            d1[1] = pk2(a1[2], a1[3]);
        }
        __syncthreads();
        ushort* Yg = Y + (size_t)(b * 288 + og * 96) * HW + n0;
        #pragma unroll
        for (int p = 0; p < 6; ++p) {
            int row = p * 16 + row0;
            *(short8*)&Yg[(size_t)row * HW + 8 * g] = *(const short8*)&ys[row * 136 + 8 * g];
        }
        __syncthreads();
    }
}

// ---------------- depthwise 3x3 SAME, LDS-free, per-wave 8 rows; + SSQ ----------------
__global__ __launch_bounds__(256, 8) void dw_kernel(
        const ushort* __restrict__ Yc, const ushort* __restrict__ Yt,
        const float* __restrict__ qdw_c, const float* __restrict__ kvdw_c,
        const float* __restrict__ qdw_t, const float* __restrict__ kvdw_t,
        ushort* __restrict__ QKVc, ushort* __restrict__ QKVt,
        float* __restrict__ SSQ, int base_strm) {
    int tid = threadIdx.x, wave = tid >> 6, lane = tid & 63;
    int strm = base_strm + blockIdx.z;
    int ch = blockIdx.y % 288, b = blockIdx.y / 288;
    int r0 = blockIdx.x * 32 + wave * 8;
    const ushort* Y = strm ? Yt : Yc;
    ushort* QKV = strm ? QKVt : QKVc;
    const float* qdw = strm ? qdw_t : qdw_c;
    const float* kvdw = strm ? kvdw_t : kvdw_c;
    const float* w = (ch < 96) ? (qdw + ch * 9) : (kvdw + (ch - 96) * 9);
    float w00 = w[0], w01 = w[1], w02 = w[2], w10 = w[3], w11 = w[4],
          w12 = w[5], w20 = w[6], w21 = w[7], w22 = w[8];
    const ushort* src = Y + (size_t)(b * 288 + ch) * HW;
    float rows[3][6];
    float ssq = 0.f;
    #define LOADROW(R, D)                                                    \
    {                                                                        \
        int r_ = (R);                                                        \
        if ((unsigned)r_ < 256u) {                                           \
            ushort4 t4 = *(const ushort4*)(src + r_ * 256 + 4 * lane);       \
            float c0 = bf2f(t4.x), c1 = bf2f(t4.y), c2 = bf2f(t4.z), c3 = bf2f(t4.w); \
            float lft = __shfl(c3, lane - 1);                                \
            float rgt = __shfl(c0, lane + 1);                                \
            if (lane == 0) lft = 0.f;                                        \
            if (lane == 63) rgt = 0.f;                                       \
            D[0] = lft; D[1] = c0; D[2] = c1; D[3] = c2; D[4] = c3; D[5] = rgt; \
        } else {                                                             \
            D[0] = 0.f; D[1] = 0.f; D[2] = 0.f; D[3] = 0.f; D[4] = 0.f; D[5] = 0.f; \
        }                                                                    \
    }
    LOADROW(r0 - 1, rows[0]);
    LOADROW(r0, rows[1]);
    ushort* dst = QKV + (size_t)(b * 288 + ch) * HW;
    #pragma unroll
    for (int orow = 0; orow < 8; ++orow) {
        LOADROW(r0 + orow + 1, rows[(orow + 2) % 3]);
        float* ra = rows[orow % 3];
        float* rb = rows[(orow + 1) % 3];
        float* rc = rows[(orow + 2) % 3];
        float acc[4];
        #pragma unroll
        for (int j = 0; j < 4; ++j) {
            acc[j] = w00 * ra[j] + w01 * ra[j + 1] + w02 * ra[j + 2]
                   + w10 * rb[j] + w11 * rb[j + 1] + w12 * rb[j + 2]
                   + w20 * rc[j] + w21 * rc[j + 1] + w22 * rc[j + 2];
            ssq += acc[j] * acc[j];
        }
        uint2 pv;
        pv.x = pk2(acc[0], acc[1]);
        pv.y = pk2(acc[2], acc[3]);
        *(uint2*)&dst[(r0 + orow) * 256 + 4 * lane] = pv;
    }
    #undef LOADROW
    if (ch < 192) {
        #pragma unroll
        for (int off = 1; off < 64; off <<= 1) ssq += __shfl_xor(ssq, off);
        if (lane == 0) {
            int t_ = ch >= 96;
            int chq = t_ ? ch - 96 : ch;
            int a_ = (strm == 0) ? t_ : (1 - t_);
            atomicAdd(&SSQ[((a_ * 2 + b) * 2 + t_) * 96 + chq], ssq);
        }
    }
}

// ---------------- Gram: LDS-staged, XOR-swizzled, partials to Gpart ----------------
__global__ __launch_bounds__(256) void gram_kernel(const ushort* __restrict__ QKVc,
                                                   const ushort* __restrict__ QKVt,
                                                   float* __restrict__ Gpart) {
    __shared__ ushort qs[32 * 256];
    __shared__ ushort ks2[32 * 256];
    __shared__ float Gp[4][32][32];
    int tid = threadIdx.x, wave = tid >> 6, lane = tid & 63;
    int lr = lane & 15, lg = lane >> 4;
    int code = blockIdx.y;                        // a*6 + b*3 + h
    int a = code / 6, b = (code % 6) / 3, h = code % 3;
    const ushort* qsrc = (a == 0) ? QKVc : QKVt;
    const ushort* ksrc = (a == 0) ? QKVt : QKVc;
    const ushort* qb = qsrc + (size_t)(b * 288 + 32 * h) * HW + blockIdx.x * 1024;
    const ushort* kb = ksrc + (size_t)(b * 288 + 96 + 32 * h) * HW + blockIdx.x * 1024;
    f32x4 acc[2][2];
    #pragma unroll
    for (int i = 0; i < 2; ++i)
        #pragma unroll
        for (int j = 0; j < 2; ++j) acc[i][j] = (f32x4){0.f, 0.f, 0.f, 0.f};
    for (int ph = 0; ph < 4; ++ph) {
        int noff = ph * 256;
        #pragma unroll
        for (int i = 0; i < 4; ++i) {
            int idx = tid + i * 256;
            int row = idx >> 5, g = idx & 31;
            int col = (g * 8) ^ ((row & 7) << 3);
            *(short8*)&qs[row * 256 + col] = *(const short8*)(qb + (size_t)row * HW + noff + 8 * g);
            *(short8*)&ks2[row * 256 + col] = *(const short8*)(kb + (size_t)row * HW + noff + 8 * g);
        }
        __syncthreads();
        #pragma unroll
        for (int j = 0; j < 2; ++j) {
            int ks_ = wave * 2 + j;
            int c0 = (ks_ * 32 + lg * 8) ^ ((lr & 7) << 3);
            short8 a0 = *(const short8*)&qs[lr * 256 + c0];
            short8 a1 = *(const short8*)&qs[(16 + lr) * 256 + c0];
            short8 b0 = *(const short8*)&ks2[lr * 256 + c0];
            short8 b1 = *(const short8*)&ks2[(16 + lr) * 256 + c0];
            acc[0][0] = mfma16(a0, b0, acc[0][0]);
            acc[0][1] = mfma16(a0, b1, acc[0][1]);
            acc[1][0] = mfma16(a1, b0, acc[1][0]);
            acc[1][1] = mfma16(a1, b1, acc[1][1]);
        }
        __syncthreads();
    }
    #pragma unroll
    for (int i = 0; i < 2; ++i)
        #pragma unroll
        for (int j = 0; j < 2; ++j)
            #pragma unroll
            for (int r = 0; r < 4; ++r)
                Gp[wave][i * 16 + lg * 4 + r][j * 16 + lr] = acc[i][j][r];
    __syncthreads();
    float* Gout = Gpart + ((size_t)code * GNS + blockIdx.x) * 1024;
    for (int idx = tid; idx < 1024; idx += 256) {
        float ssum = 0.f;
        #pragma unroll
        for (int wv = 0; wv < 4; ++wv) ssum += (&Gp[wv][0][0])[idx];
        Gout[idx] = ssum;
    }
}

// ---------------- reduce partials + softmax + fold attn into M matrices ----------------
__global__ __launch_bounds__(256) void attn_kernel(const float* __restrict__ Gpart,
                                                   const float* __restrict__ SSQ,
                                                   const float* __restrict__ temperature,
                                                   const float* __restrict__ W1,
                                                   const float* __restrict__ W2,
                                                   ushort* __restrict__ Mcat) {
    __shared__ float Gs[1024];
    __shared__ float nq[32], nk[32], A[32][32];
    int tid = threadIdx.x;
    int code = blockIdx.x;
    int a = code / 6, b = (code % 6) / 3, h = code % 3;
    const float* gp = Gpart + (size_t)code * GNS * 1024;
    #pragma unroll
    for (int j = 0; j < 4; ++j) {
        int idx = tid + j * 256;
        float s = 0.f;
        #pragma unroll 8
        for (int p = 0; p < GNS; ++p) s += gp[(size_t)p * 1024 + idx];
        Gs[idx] = s;
    }
    if (tid < 32)
        nq[tid] = fmaxf(sqrtf(fmaxf(SSQ[((a * 2 + b) * 2 + 0) * 96 + 32 * h + tid], 0.f)), 1e-12f);
    else if (tid < 64)
        nk[tid - 32] = fmaxf(sqrtf(fmaxf(SSQ[((a * 2 + b) * 2 + 1) * 96 + 32 * h + (tid - 32)], 0.f)), 1e-12f);
    __syncthreads();
    if (tid < 32) {
        float t = temperature[h];
        float lgv[32];
        float inq = t / nq[tid];
        float mx = -1e30f;
        #pragma unroll
        for (int j = 0; j < 32; ++j) { lgv[j] = Gs[tid * 32 + j] * inq / nk[j]; mx = fmaxf(mx, lgv[j]); }
        float ssum = 0.f;
        #pragma unroll
        for (int j = 0; j < 32; ++j) { lgv[j] = expf(lgv[j] - mx); ssum += lgv[j]; }
        float inv = 1.f / ssum;
        #pragma unroll
        for (int j = 0; j < 32; ++j) A[tid][j] = lgv[j] * inv;
    }
    __syncthreads();
    const float* Wm = (a == 0) ? W1 : W2;
    for (int idx = tid; idx < 96 * 32; idx += 256) {
        int o = idx >> 5, d = idx & 31;
        float acc = 0.f;
        #pragma unroll
        for (int i = 0; i < 32; ++i)
            acc += Wm[o * 96 + 32 * h + i] * A[i][d];
        Mcat[(size_t)(b * 96 + o) * 192 + a * 96 + 32 * h + d] = f2bf(acc);
    }
}

// ---------------- final: MFMA -> fp32 LDS restage -> contiguous stores ----------------
__global__ __launch_bounds__(256, 2) void final_kernel(const ushort* __restrict__ QKVc,
                                                       const ushort* __restrict__ QKVt,
                                                       const ushort* __restrict__ Mcat,
                                                       const float* __restrict__ bias,
                                                       float* __restrict__ out) {
    __shared__ float smem[96 * 132];              // ushort[192][132] staging, then float[96][132]
    ushort* vs = (ushort*)smem;                   // stride 132 ushorts
    int tid = threadIdx.x;
    int n0 = blockIdx.x * 128, b = blockIdx.y;
    int wave = tid >> 6, lane = tid & 63, lr = lane & 15, lg = lane >> 4;
    #pragma unroll
    for (int i = 0; i < 12; ++i) {
        int idx = tid + i * 256;                  // 3072 = 192 d x 16 granules
        int d = idx >> 4, g = idx & 15;
        const ushort* sp = (d < 96) ? (QKVt + (size_t)(b * 288 + 192 + d) * HW)
                                    : (QKVc + (size_t)(b * 288 + 192 + (d - 96)) * HW);
        U8 t;
        t.s = *(const short8*)(sp + n0 + 8 * g);
        unsigned* dst = (unsigned*)&vs[d * 132 + 8 * g];
        dst[0] = t.u[0]; dst[1] = t.u[1]; dst[2] = t.u[2]; dst[3] = t.u[3];
    }
    __syncthreads();
    short8 vf[2][6];
    #pragma unroll
    for (int nt = 0; nt < 2; ++nt) {
        int n = wave * 32 + nt * 16 + lr;
        #pragma unroll
        for (int kk = 0; kk < 6; ++kk) {
            int kb = kk * 32 + lg * 8;
            U8 t;
            #pragma unroll
            for (int j = 0; j < 4; ++j) {
                unsigned e0 = vs[(kb + 2 * j) * 132 + n];
                unsigned e1 = vs[(kb + 2 * j + 1) * 132 + n];
                t.u[j] = e0 | (e1 << 16);
            }
            vf[nt][kk] = t.s;
        }
    }
    __syncthreads();                              // vs reads complete; safe to overwrite
    const ushort* Mb = Mcat + (size_t)b * 96 * 192;
    #pragma unroll
    for (int mt = 0; mt < 6; ++mt) {
        f32x4 a0 = {0.f, 0.f, 0.f, 0.f}, a1 = {0.f, 0.f, 0.f, 0.f};
        #pragma unroll
        for (int kk = 0; kk < 6; ++kk) {
            short8 mf = *(const short8*)&Mb[(size_t)(mt * 16 + lr) * 192 + kk * 32 + lg * 8];
            a0 = mfma16(vf[0][kk], mf, a0);
            a1 = mfma16(vf[1][kk], mf, a1);
        }
        *(float4*)&smem[(mt * 16 + lr) * 132 + wave * 32 + lg * 4] =
            make_float4(a0[0], a0[1], a0[2], a0[3]);
        *(float4*)&smem[(mt * 16 + lr) * 132 + wave * 32 + 16 + lg * 4] =
            make_float4(a1[0], a1[1], a1[2], a1[3]);
    }
    __syncthreads();
    float* outb = out + (size_t)b * 96 * HW + n0;
    int row0 = tid >> 5, q = tid & 31;
    #pragma unroll
    for (int p = 0; p < 12; ++p) {
        int row = p * 8 + row0;
        float4 v = *(const float4*)&smem[row * 132 + 4 * q];
        float bb = bias[row];
        v.x += bb; v.y += bb; v.z += bb; v.w += bb;
        *(float4*)&outb[(size_t)row * HW + 4 * q] = v;
    }
}

extern "C" void kernel_launch(void* const* d_in, const int* in_sizes, int n_in,
                              void* d_out, int out_size, void* d_ws, size_t ws_size,
                              hipStream_t stream) {
    const float* low    = (const float*)d_in[0];
    const float* high   = (const float*)d_in[1];
    const float* temp   = (const float*)d_in[2];
    const float* qc_w   = (const float*)d_in[3];
    const float* qdw_c  = (const float*)d_in[4];
    const float* kvc_w  = (const float*)d_in[5];
    const float* kvdw_c = (const float*)d_in[6];
    const float* qt_w   = (const float*)d_in[7];
    const float* qdw_t  = (const float*)d_in[8];
    const float* kvt_w  = (const float*)d_in[9];
    const float* kvdw_t = (const float*)d_in[10];
    const float* po_c   = (const float*)d_in[11];
    const float* po_t   = (const float*)d_in[12];
    const float* cw     = (const float*)d_in[13];
    const float* cb     = (const float*)d_in[14];
    float* out = (float*)d_out;

    char* ws = (char*)d_ws;
    const size_t SY = (size_t)2 * 288 * HW * 2;   // 75,497,472 B per big tensor
    const size_t EXTRA = 2 * (size_t)(288 * 96 * 2) + 2 * (size_t)(96 * 96 * 4)
                       + (size_t)(8 * 96 * 4) + (size_t)(2 * 96 * 192 * 2);
    bool merged = (ws_size >= 4 * SY + EXTRA);
    size_t nbig = merged ? 4 : 3;
    ushort* B0 = (ushort*)(ws);                   // Yc (merged) / Y (fallback)
    ushort* B1 = (ushort*)(ws + SY);              // Yt (merged) / QKVc (fallback)
    ushort* B2 = (ushort*)(ws + 2 * SY);          // QKVc (merged) / QKVt (fallback)
    ushort* B3 = (ushort*)(ws + 3 * SY);          // QKVt (merged only)
    float* Gpart = (float*)ws;                    // overlays B0 (dead after dw)
    char* p = ws + nbig * SY;
    ushort* Wc = (ushort*)p; p += 288 * 96 * 2;
    ushort* Wt = (ushort*)p; p += 288 * 96 * 2;
    float* W1  = (float*)p;  p += 96 * 96 * 4;
    float* W2  = (float*)p;  p += 96 * 96 * 4;
    float* SSQ = (float*)p;  p += 8 * 96 * 4;
    ushort* Mcat = (ushort*)p; p += 2 * 96 * 192 * 2;
    if ((size_t)(p - ws) > ws_size) return;

    prep_kernel<<<81, 256, 0, stream>>>(qc_w, kvc_w, qt_w, kvt_w, cw, po_c, po_t, Wc, Wt, W1, W2, SSQ);
    ushort* QKVc;
    ushort* QKVt;
    if (merged) {
        QKVc = B2; QKVt = B3;
        conv_kernel<<<dim3(512, 2, 2), 256, 0, stream>>>(high, low, Wc, Wt, B0, B1);
        dw_kernel<<<dim3(8, 576, 2), 256, 0, stream>>>(B0, B1, qdw_c, kvdw_c, qdw_t, kvdw_t,
                                                       QKVc, QKVt, SSQ, 0);
    } else {
        QKVc = B1; QKVt = B2;
        conv_kernel<<<dim3(512, 2, 1), 256, 0, stream>>>(high, high, Wc, Wc, B0, B0);
        dw_kernel<<<dim3(8, 576, 1), 256, 0, stream>>>(B0, B0, qdw_c, kvdw_c, qdw_c, kvdw_c,
                                                       QKVc, QKVc, SSQ, 0);
        conv_kernel<<<dim3(512, 2, 1), 256, 0, stream>>>(low, low, Wt, Wt, B0, B0);
        dw_kernel<<<dim3(8, 576, 1), 256, 0, stream>>>(B0, B0, qdw_t, kvdw_t, qdw_t, kvdw_t,
                                                       QKVt, QKVt, SSQ, 1);
    }
    gram_kernel<<<dim3(GNS, 12), 256, 0, stream>>>(QKVc, QKVt, Gpart);
    attn_kernel<<<12, 256, 0, stream>>>(Gpart, SSQ, temp, W1, W2, Mcat);
    final_kernel<<<dim3(512, 2), 256, 0, stream>>>(QKVc, QKVt, Mcat, cb, out);
}

// Round 11
// 230.532 us; speedup vs baseline: 1.2592x; 1.0192x over previous
//
#include <hip/hip_runtime.h>
#include <hip/hip_bf16.h>

#define HW 65536
#define GNS 64

typedef __attribute__((ext_vector_type(8))) short short8;
typedef __attribute__((ext_vector_type(4))) float f32x4;
union U8 { short8 s; unsigned u[4]; ushort h[8]; };

static __device__ __forceinline__ ushort f2bf(float f) {
    union { float f; unsigned u; } v; v.f = f;
    unsigned u = v.u;
    unsigned r = (u + 0x7fffu + ((u >> 16) & 1u)) >> 16;
    return (ushort)r;
}
static __device__ __forceinline__ float bf2f(ushort u) {
    union { unsigned u; float f; } v; v.u = ((unsigned)u) << 16; return v.f;
}
static __device__ __forceinline__ unsigned pk2(float a, float b) {
    __hip_bfloat162 h = __float22bfloat162_rn(make_float2(a, b));
    union { __hip_bfloat162 h; unsigned u; } c; c.h = h; return c.u;
}
static __device__ __forceinline__ f32x4 mfma16(short8 a, short8 b, f32x4 c) {
    return __builtin_amdgcn_mfma_f32_16x16x32_bf16(a, b, c, 0, 0, 0);
}

// ---------------- prep: pack conv weights bf16; fold W1/W2; zero SSQ ----------------
__global__ __launch_bounds__(256) void prep_kernel(
        const float* __restrict__ qc, const float* __restrict__ kvc,
        const float* __restrict__ qt, const float* __restrict__ kvt,
        const float* __restrict__ cw, const float* __restrict__ poc, const float* __restrict__ pot,
        ushort* __restrict__ Wc, ushort* __restrict__ Wt,
        float* __restrict__ W1, float* __restrict__ W2, float* __restrict__ SSQ) {
    int bx = blockIdx.x, tid = threadIdx.x;
    if (bx < 9) {
        for (int idx = bx * 256 + tid; idx < 288 * 96; idx += 9 * 256) {
            Wc[idx] = f2bf(idx < 96 * 96 ? qc[idx] : kvc[idx - 96 * 96]);
            Wt[idx] = f2bf(idx < 96 * 96 ? qt[idx] : kvt[idx - 96 * 96]);
        }
        if (bx == 0)
            for (int idx = tid; idx < 8 * 96; idx += 256) SSQ[idx] = 0.f;
    } else {
        int idx = (bx - 9) * 256 + tid;          // 0..18431
        int sel = idx < 9216 ? 0 : 1;
        int i = sel ? idx - 9216 : idx;
        int o = i / 96, m = i % 96;
        const float* po = sel ? pot : poc;
        float acc = 0.f;
        for (int p = 0; p < 96; ++p)
            acc += cw[o * 192 + sel * 96 + p] * po[p * 96 + m];
        (sel ? W2 : W1)[i] = acc;
    }
}

// ---------------- conv1x1 (both streams via blockIdx.z) ----------------
__global__ __launch_bounds__(256, 2) void conv_kernel(
        const float* __restrict__ Xc, const float* __restrict__ Xt,
        const ushort* __restrict__ Wcp, const ushort* __restrict__ Wtp,
        ushort* __restrict__ Yco, ushort* __restrict__ Yto) {
    __shared__ ushort xs[96][136];
    int strm = blockIdx.z;
    const float* X = strm ? Xt : Xc;
    const ushort* W = strm ? Wtp : Wcp;
    ushort* Y = strm ? Yto : Yco;
    int tid = threadIdx.x;
    int n0 = blockIdx.x * 128;
    int b = blockIdx.y;
    int wave = tid >> 6, lane = tid & 63, lr = lane & 15, lg = lane >> 4;
    const float* Xb = X + (size_t)b * 96 * HW + n0;
    #pragma unroll
    for (int i = 0; i < 12; ++i) {
        int idx = tid + i * 256;
        int ch = idx >> 5, g = idx & 31;
        float4 v = *(const float4*)(Xb + (size_t)ch * HW + 4 * g);
        unsigned* d = (unsigned*)&xs[ch][4 * g];
        d[0] = pk2(v.x, v.y);
        d[1] = pk2(v.z, v.w);
    }
    __syncthreads();
    short8 af[2][3];
    #pragma unroll
    for (int nt = 0; nt < 2; ++nt) {
        int n = wave * 32 + nt * 16 + lr;
        #pragma unroll
        for (int kk = 0; kk < 3; ++kk) {
            int kb = kk * 32 + lg * 8;
            U8 t;
            #pragma unroll
            for (int j = 0; j < 4; ++j) {
                unsigned e0 = xs[kb + 2 * j][n];
                unsigned e1 = xs[kb + 2 * j + 1][n];
                t.u[j] = e0 | (e1 << 16);
            }
            af[nt][kk] = t.s;
        }
    }
    __syncthreads();
    ushort* ys = &xs[0][0];
    int row0 = tid >> 4, g = tid & 15;
    for (int og = 0; og < 3; ++og) {
        const ushort* Wg = W + (size_t)og * 96 * 96 + (size_t)lr * 96 + lg * 8;
        #pragma unroll
        for (int mt = 0; mt < 6; ++mt) {
            f32x4 a0 = {0.f, 0.f, 0.f, 0.f}, a1 = {0.f, 0.f, 0.f, 0.f};
            #pragma unroll
            for (int kk = 0; kk < 3; ++kk) {
                short8 wf = *(const short8*)(Wg + (size_t)mt * 16 * 96 + kk * 32);
                a0 = mfma16(af[0][kk], wf, a0);
                a1 = mfma16(af[1][kk], wf, a1);
            }
            unsigned* d0 = (unsigned*)&ys[(mt * 16 + lr) * 136 + wave * 32 + lg * 4];
            d0[0] = pk2(a0[0], a0[1]);
            d0[1] = pk2(a0[2], a0[3]);
            unsigned* d1 = (unsigned*)&ys[(mt * 16 + lr) * 136 + wave * 32 + 16 + lg * 4];
            d1[0] = pk2(a1[0], a1[1]);
            d1[1] = pk2(a1[2], a1[3]);
        }
        __syncthreads();
        ushort* Yg = Y + (size_t)(b * 288 + og * 96) * HW + n0;
        #pragma unroll
        for (int p = 0; p < 6; ++p) {
            int row = p * 16 + row0;
            *(short8*)&Yg[(size_t)row * HW + 8 * g] = *(const short8*)&ys[row * 136 + 8 * g];
        }
        __syncthreads();
    }
}

#define DW_LOADROW(R, D)                                                     \
{                                                                            \
    int r_ = (R);                                                            \
    if ((unsigned)r_ < 256u) {                                               \
        ushort4 t4 = *(const ushort4*)(src + r_ * 256 + 4 * lane);           \
        float c0 = bf2f(t4.x), c1 = bf2f(t4.y), c2 = bf2f(t4.z), c3 = bf2f(t4.w); \
        float lft = __shfl(c3, lane - 1);                                    \
        float rgt = __shfl(c0, lane + 1);                                    \
        if (lane == 0) lft = 0.f;                                            \
        if (lane == 63) rgt = 0.f;                                           \
        D[0] = lft; D[1] = c0; D[2] = c1; D[3] = c2; D[4] = c3; D[5] = rgt;  \
    } else {                                                                 \
        D[0] = 0.f; D[1] = 0.f; D[2] = 0.f; D[3] = 0.f; D[4] = 0.f; D[5] = 0.f; \
    }                                                                        \
}

// ---------------- depthwise 3x3, q/k channels only (192), LDS-free; + SSQ ----------------
__global__ __launch_bounds__(256, 8) void dwqk_kernel(
        const ushort* __restrict__ Yc, const ushort* __restrict__ Yt,
        const float* __restrict__ qdw_c, const float* __restrict__ kvdw_c,
        const float* __restrict__ qdw_t, const float* __restrict__ kvdw_t,
        ushort* __restrict__ QKVc, ushort* __restrict__ QKVt,
        float* __restrict__ SSQ) {
    int tid = threadIdx.x, wave = tid >> 6, lane = tid & 63;
    int strm = blockIdx.z;
    int ch = blockIdx.y % 192, b = blockIdx.y / 192;
    int r0 = blockIdx.x * 32 + wave * 8;
    const ushort* Y = strm ? Yt : Yc;
    ushort* QKV = strm ? QKVt : QKVc;
    const float* qdw = strm ? qdw_t : qdw_c;
    const float* kvdw = strm ? kvdw_t : kvdw_c;
    const float* w = (ch < 96) ? (qdw + ch * 9) : (kvdw + (ch - 96) * 9);
    float w00 = w[0], w01 = w[1], w02 = w[2], w10 = w[3], w11 = w[4],
          w12 = w[5], w20 = w[6], w21 = w[7], w22 = w[8];
    const ushort* src = Y + (size_t)(b * 288 + ch) * HW;
    float rows[3][6];
    float ssq = 0.f;
    DW_LOADROW(r0 - 1, rows[0]);
    DW_LOADROW(r0, rows[1]);
    ushort* dst = QKV + (size_t)(b * 288 + ch) * HW;
    #pragma unroll
    for (int orow = 0; orow < 8; ++orow) {
        DW_LOADROW(r0 + orow + 1, rows[(orow + 2) % 3]);
        float* ra = rows[orow % 3];
        float* rb = rows[(orow + 1) % 3];
        float* rc = rows[(orow + 2) % 3];
        float acc[4];
        #pragma unroll
        for (int j = 0; j < 4; ++j) {
            acc[j] = w00 * ra[j] + w01 * ra[j + 1] + w02 * ra[j + 2]
                   + w10 * rb[j] + w11 * rb[j + 1] + w12 * rb[j + 2]
                   + w20 * rc[j] + w21 * rc[j + 1] + w22 * rc[j + 2];
            ssq += acc[j] * acc[j];
        }
        uint2 pv;
        pv.x = pk2(acc[0], acc[1]);
        pv.y = pk2(acc[2], acc[3]);
        *(uint2*)&dst[(r0 + orow) * 256 + 4 * lane] = pv;
    }
    #pragma unroll
    for (int off = 1; off < 64; off <<= 1) ssq += __shfl_xor(ssq, off);
    if (lane == 0) {
        int t_ = ch >= 96;
        int chq = t_ ? ch - 96 : ch;
        int a_ = (strm == 0) ? t_ : (1 - t_);
        atomicAdd(&SSQ[((a_ * 2 + b) * 2 + t_) * 96 + chq], ssq);
    }
}

// ---------------- full depthwise (fallback path only) ----------------
__global__ __launch_bounds__(256, 8) void dwfull_kernel(
        const ushort* __restrict__ Y, const float* __restrict__ qdw,
        const float* __restrict__ kvdw, ushort* __restrict__ QKV,
        float* __restrict__ SSQ, int strm) {
    int tid = threadIdx.x, wave = tid >> 6, lane = tid & 63;
    int ch = blockIdx.y % 288, b = blockIdx.y / 288;
    int r0 = blockIdx.x * 32 + wave * 8;
    const float* w = (ch < 96) ? (qdw + ch * 9) : (kvdw + (ch - 96) * 9);
    float w00 = w[0], w01 = w[1], w02 = w[2], w10 = w[3], w11 = w[4],
          w12 = w[5], w20 = w[6], w21 = w[7], w22 = w[8];
    const ushort* src = Y + (size_t)(b * 288 + ch) * HW;
    float rows[3][6];
    float ssq = 0.f;
    DW_LOADROW(r0 - 1, rows[0]);
    DW_LOADROW(r0, rows[1]);
    ushort* dst = QKV + (size_t)(b * 288 + ch) * HW;
    #pragma unroll
    for (int orow = 0; orow < 8; ++orow) {
        DW_LOADROW(r0 + orow + 1, rows[(orow + 2) % 3]);
        float* ra = rows[orow % 3];
        float* rb = rows[(orow + 1) % 3];
        float* rc = rows[(orow + 2) % 3];
        float acc[4];
        #pragma unroll
        for (int j = 0; j < 4; ++j) {
            acc[j] = w00 * ra[j] + w01 * ra[j + 1] + w02 * ra[j + 2]
                   + w10 * rb[j] + w11 * rb[j + 1] + w12 * rb[j + 2]
                   + w20 * rc[j] + w21 * rc[j + 1] + w22 * rc[j + 2];
            ssq += acc[j] * acc[j];
        }
        uint2 pv;
        pv.x = pk2(acc[0], acc[1]);
        pv.y = pk2(acc[2], acc[3]);
        *(uint2*)&dst[(r0 + orow) * 256 + 4 * lane] = pv;
    }
    if (ch < 192) {
        #pragma unroll
        for (int off = 1; off < 64; off <<= 1) ssq += __shfl_xor(ssq, off);
        if (lane == 0) {
            int t_ = ch >= 96;
            int chq = t_ ? ch - 96 : ch;
            int a_ = (strm == 0) ? t_ : (1 - t_);
            atomicAdd(&SSQ[((a_ * 2 + b) * 2 + t_) * 96 + chq], ssq);
        }
    }
}

// ---------------- merged: Gram (x<gns) + depthwise-v (x>=gns) ----------------
__global__ __launch_bounds__(256) void gram_dwv_kernel(
        ushort* __restrict__ QKVc, ushort* __restrict__ QKVt,
        float* __restrict__ Gpart,
        const ushort* __restrict__ Yc, const ushort* __restrict__ Yt,
        const float* __restrict__ kvdw_c, const float* __restrict__ kvdw_t,
        int gns) {
    __shared__ ushort qs[32 * 256];
    __shared__ ushort ks2[32 * 256];
    __shared__ float Gp[4][32][32];
    int tid = threadIdx.x, wave = tid >> 6, lane = tid & 63;
    if ((int)blockIdx.x >= gns) {
        // -------- depthwise on v channels (96 per stream) --------
        int flat = ((int)blockIdx.x - gns) * 12 + (int)blockIdx.y;   // 0..3071
        int rg = flat & 7, cc = flat >> 3;                           // cc 0..383
        int strm = cc / 192, rem = cc % 192;
        int b = rem / 96, cv = rem % 96;
        int r0 = rg * 32 + wave * 8;
        const ushort* Y = strm ? Yt : Yc;
        ushort* QKV = strm ? QKVt : QKVc;
        const float* kvdw = strm ? kvdw_t : kvdw_c;
        const float* w = kvdw + (96 + cv) * 9;
        float w00 = w[0], w01 = w[1], w02 = w[2], w10 = w[3], w11 = w[4],
              w12 = w[5], w20 = w[6], w21 = w[7], w22 = w[8];
        const ushort* src = Y + (size_t)(b * 288 + 192 + cv) * HW;
        float rows[3][6];
        DW_LOADROW(r0 - 1, rows[0]);
        DW_LOADROW(r0, rows[1]);
        ushort* dst = QKV + (size_t)(b * 288 + 192 + cv) * HW;
        #pragma unroll
        for (int orow = 0; orow < 8; ++orow) {
            DW_LOADROW(r0 + orow + 1, rows[(orow + 2) % 3]);
            float* ra = rows[orow % 3];
            float* rb = rows[(orow + 1) % 3];
            float* rc = rows[(orow + 2) % 3];
            float acc[4];
            #pragma unroll
            for (int j = 0; j < 4; ++j)
                acc[j] = w00 * ra[j] + w01 * ra[j + 1] + w02 * ra[j + 2]
                       + w10 * rb[j] + w11 * rb[j + 1] + w12 * rb[j + 2]
                       + w20 * rc[j] + w21 * rc[j + 1] + w22 * rc[j + 2];
            uint2 pv;
            pv.x = pk2(acc[0], acc[1]);
            pv.y = pk2(acc[2], acc[3]);
            *(uint2*)&dst[(r0 + orow) * 256 + 4 * lane] = pv;
        }
        return;
    }
    // -------- Gram --------
    int lr = lane & 15, lg = lane >> 4;
    int code = blockIdx.y;                        // a*6 + b*3 + h
    int a = code / 6, b = (code % 6) / 3, h = code % 3;
    const ushort* qsrc = (a == 0) ? QKVc : QKVt;
    const ushort* ksrc = (a == 0) ? QKVt : QKVc;
    const ushort* qb = qsrc + (size_t)(b * 288 + 32 * h) * HW + blockIdx.x * 1024;
    const ushort* kb = ksrc + (size_t)(b * 288 + 96 + 32 * h) * HW + blockIdx.x * 1024;
    f32x4 acc[2][2];
    #pragma unroll
    for (int i = 0; i < 2; ++i)
        #pragma unroll
        for (int j = 0; j < 2; ++j) acc[i][j] = (f32x4){0.f, 0.f, 0.f, 0.f};
    for (int ph = 0; ph < 4; ++ph) {
        int noff = ph * 256;
        #pragma unroll
        for (int i = 0; i < 4; ++i) {
            int idx = tid + i * 256;
            int row = idx >> 5, g = idx & 31;
            int col = (g * 8) ^ ((row & 7) << 3);
            *(short8*)&qs[row * 256 + col] = *(const short8*)(qb + (size_t)row * HW + noff + 8 * g);
            *(short8*)&ks2[row * 256 + col] = *(const short8*)(kb + (size_t)row * HW + noff + 8 * g);
        }
        __syncthreads();
        #pragma unroll
        for (int j = 0; j < 2; ++j) {
            int ks_ = wave * 2 + j;
            int c0 = (ks_ * 32 + lg * 8) ^ ((lr & 7) << 3);
            short8 a0 = *(const short8*)&qs[lr * 256 + c0];
            short8 a1 = *(const short8*)&qs[(16 + lr) * 256 + c0];
            short8 b0 = *(const short8*)&ks2[lr * 256 + c0];
            short8 b1 = *(const short8*)&ks2[(16 + lr) * 256 + c0];
            acc[0][0] = mfma16(a0, b0, acc[0][0]);
            acc[0][1] = mfma16(a0, b1, acc[0][1]);
            acc[1][0] = mfma16(a1, b0, acc[1][0]);
            acc[1][1] = mfma16(a1, b1, acc[1][1]);
        }
        __syncthreads();
    }
    #pragma unroll
    for (int i = 0; i < 2; ++i)
        #pragma unroll
        for (int j = 0; j < 2; ++j)
            #pragma unroll
            for (int r = 0; r < 4; ++r)
                Gp[wave][i * 16 + lg * 4 + r][j * 16 + lr] = acc[i][j][r];
    __syncthreads();
    float* Gout = Gpart + ((size_t)code * GNS + blockIdx.x) * 1024;
    for (int idx = tid; idx < 1024; idx += 256) {
        float ssum = 0.f;
        #pragma unroll
        for (int wv = 0; wv < 4; ++wv) ssum += (&Gp[wv][0][0])[idx];
        Gout[idx] = ssum;
    }
}

// ---------------- reduce partials + softmax + fold attn into M matrices ----------------
__global__ __launch_bounds__(256) void attn_kernel(const float* __restrict__ Gpart,
                                                   const float* __restrict__ SSQ,
                                                   const float* __restrict__ temperature,
                                                   const float* __restrict__ W1,
                                                   const float* __restrict__ W2,
                                                   ushort* __restrict__ Mcat) {
    __shared__ float Gs[1024];
    __shared__ float nq[32], nk[32], A[32][32];
    int tid = threadIdx.x;
    int code = blockIdx.x;
    int a = code / 6, b = (code % 6) / 3, h = code % 3;
    const float* gp = Gpart + (size_t)code * GNS * 1024;
    #pragma unroll
    for (int j = 0; j < 4; ++j) {
        int idx = tid + j * 256;
        float s = 0.f;
        #pragma unroll 8
        for (int p = 0; p < GNS; ++p) s += gp[(size_t)p * 1024 + idx];
        Gs[idx] = s;
    }
    if (tid < 32)
        nq[tid] = fmaxf(sqrtf(fmaxf(SSQ[((a * 2 + b) * 2 + 0) * 96 + 32 * h + tid], 0.f)), 1e-12f);
    else if (tid < 64)
        nk[tid - 32] = fmaxf(sqrtf(fmaxf(SSQ[((a * 2 + b) * 2 + 1) * 96 + 32 * h + (tid - 32)], 0.f)), 1e-12f);
    __syncthreads();
    if (tid < 32) {
        float t = temperature[h];
        float lgv[32];
        float inq = t / nq[tid];
        float mx = -1e30f;
        #pragma unroll
        for (int j = 0; j < 32; ++j) { lgv[j] = Gs[tid * 32 + j] * inq / nk[j]; mx = fmaxf(mx, lgv[j]); }
        float ssum = 0.f;
        #pragma unroll
        for (int j = 0; j < 32; ++j) { lgv[j] = expf(lgv[j] - mx); ssum += lgv[j]; }
        float inv = 1.f / ssum;
        #pragma unroll
        for (int j = 0; j < 32; ++j) A[tid][j] = lgv[j] * inv;
    }
    __syncthreads();
    const float* Wm = (a == 0) ? W1 : W2;
    for (int idx = tid; idx < 96 * 32; idx += 256) {
        int o = idx >> 5, d = idx & 31;
        float acc = 0.f;
        #pragma unroll
        for (int i = 0; i < 32; ++i)
            acc += Wm[o * 96 + 32 * h + i] * A[i][d];
        Mcat[(size_t)(b * 96 + o) * 192 + a * 96 + 32 * h + d] = f2bf(acc);
    }
}

// ---------------- final: K-split (half LDS), persistent acc, restaged stores ----------------
__global__ __launch_bounds__(256, 2) void final_kernel(const ushort* __restrict__ QKVc,
                                                       const ushort* __restrict__ QKVt,
                                                       const ushort* __restrict__ Mcat,
                                                       const float* __restrict__ bias,
                                                       float* __restrict__ out) {
    __shared__ float smem[48 * 132];              // 25344 B; aliased ushort[96][132]
    ushort* vs = (ushort*)smem;
    int tid = threadIdx.x;
    int n0 = blockIdx.x * 128, b = blockIdx.y;
    int wave = tid >> 6, lane = tid & 63, lr = lane & 15, lg = lane >> 4;
    f32x4 acc[6][2];
    #pragma unroll
    for (int mt = 0; mt < 6; ++mt) {
        acc[mt][0] = (f32x4){0.f, 0.f, 0.f, 0.f};
        acc[mt][1] = (f32x4){0.f, 0.f, 0.f, 0.f};
    }
    const ushort* Mb = Mcat + (size_t)b * 96 * 192;
    for (int half = 0; half < 2; ++half) {
        #pragma unroll
        for (int i = 0; i < 6; ++i) {
            int idx = tid + i * 256;              // 1536 = 96 d x 16 granules
            int dl = idx >> 4, g = idx & 15;
            int d = half * 96 + dl;
            const ushort* sp = (d < 96) ? (QKVt + (size_t)(b * 288 + 192 + d) * HW)
                                        : (QKVc + (size_t)(b * 288 + 192 + (d - 96)) * HW);
            U8 t;
            t.s = *(const short8*)(sp + n0 + 8 * g);
            unsigned* dst = (unsigned*)&vs[dl * 132 + 8 * g];
            dst[0] = t.u[0]; dst[1] = t.u[1]; dst[2] = t.u[2]; dst[3] = t.u[3];
        }
        __syncthreads();
        short8 vf[2][3];
        #pragma unroll
        for (int nt = 0; nt < 2; ++nt) {
            int n = wave * 32 + nt * 16 + lr;
            #pragma unroll
            for (int kk = 0; kk < 3; ++kk) {
                int kb = kk * 32 + lg * 8;
                U8 t;
                #pragma unroll
                for (int j = 0; j < 4; ++j) {
                    unsigned e0 = vs[(kb + 2 * j) * 132 + n];
                    unsigned e1 = vs[(kb + 2 * j + 1) * 132 + n];
                    t.u[j] = e0 | (e1 << 16);
                }
                vf[nt][kk] = t.s;
            }
        }
        __syncthreads();                          // vs reads done before next overwrite
        #pragma unroll
        for (int mt = 0; mt < 6; ++mt)
            #pragma unroll
            for (int kk = 0; kk < 3; ++kk) {
                short8 mf = *(const short8*)&Mb[(size_t)(mt * 16 + lr) * 192 + half * 96 + kk * 32 + lg * 8];
                acc[mt][0] = mfma16(vf[0][kk], mf, acc[mt][0]);
                acc[mt][1] = mfma16(vf[1][kk], mf, acc[mt][1]);
            }
    }
    float* outb = out + (size_t)b * 96 * HW + n0;
    #pragma unroll
    for (int half = 0; half < 2; ++half) {
        #pragma unroll
        for (int m = 0; m < 3; ++m) {
            int mt = half * 3 + m;
            *(float4*)&smem[(m * 16 + lr) * 132 + wave * 32 + lg * 4] =
                make_float4(acc[mt][0][0], acc[mt][0][1], acc[mt][0][2], acc[mt][0][3]);
            *(float4*)&smem[(m * 16 + lr) * 132 + wave * 32 + 16 + lg * 4] =
                make_float4(acc[mt][1][0], acc[mt][1][1], acc[mt][1][2], acc[mt][1][3]);
        }
        __syncthreads();
        #pragma unroll
        for (int i = 0; i < 6; ++i) {
            int idx = tid + i * 256;              // 1536 = 48 rows x 32 quads
            int row = idx >> 5, q = idx & 31;
            float4 v = *(const float4*)&smem[row * 132 + 4 * q];
            int grow = half * 48 + row;
            float bb = bias[grow];
            v.x += bb; v.y += bb; v.z += bb; v.w += bb;
            *(float4*)&outb[(size_t)grow * HW + 4 * q] = v;
        }
        __syncthreads();
    }
}

extern "C" void kernel_launch(void* const* d_in, const int* in_sizes, int n_in,
                              void* d_out, int out_size, void* d_ws, size_t ws_size,
                              hipStream_t stream) {
    const float* low    = (const float*)d_in[0];
    const float* high   = (const float*)d_in[1];
    const float* temp   = (const float*)d_in[2];
    const float* qc_w   = (const float*)d_in[3];
    const float* qdw_c  = (const float*)d_in[4];
    const float* kvc_w  = (const float*)d_in[5];
    const float* kvdw_c = (const float*)d_in[6];
    const float* qt_w   = (const float*)d_in[7];
    const float* qdw_t  = (const float*)d_in[8];
    const float* kvt_w  = (const float*)d_in[9];
    const float* kvdw_t = (const float*)d_in[10];
    const float* po_c   = (const float*)d_in[11];
    const float* po_t   = (const float*)d_in[12];
    const float* cw     = (const float*)d_in[13];
    const float* cb     = (const float*)d_in[14];
    float* out = (float*)d_out;

    char* ws = (char*)d_ws;
    const size_t SY = (size_t)2 * 288 * HW * 2;   // 75,497,472 B per big tensor
    const size_t EXTRA = 2 * (size_t)(288 * 96 * 2) + 2 * (size_t)(96 * 96 * 4)
                       + (size_t)(8 * 96 * 4) + (size_t)(2 * 96 * 192 * 2);
    bool merged = (ws_size >= 4 * SY + EXTRA);
    size_t nbig = merged ? 4 : 3;
    ushort* B0 = (ushort*)(ws);                   // Yc (merged) / Y (fallback)
    ushort* B1 = (ushort*)(ws + SY);              // Yt (merged) / QKVc (fallback)
    ushort* B2 = (ushort*)(ws + 2 * SY);          // QKVc (merged) / QKVt (fallback)
    ushort* B3 = (ushort*)(ws + 3 * SY);          // QKVt (merged only)
    // Gpart (3.1 MB) overlays B0: merged -> Yc's q/k region (dead after dwqk,
    // dwv only reads Yc at byte offsets >= 25 MB); fallback -> Y (dead after dw).
    float* Gpart = (float*)ws;
    char* p = ws + nbig * SY;
    ushort* Wc = (ushort*)p; p += 288 * 96 * 2;
    ushort* Wt = (ushort*)p; p += 288 * 96 * 2;
    float* W1  = (float*)p;  p += 96 * 96 * 4;
    float* W2  = (float*)p;  p += 96 * 96 * 4;
    float* SSQ = (float*)p;  p += 8 * 96 * 4;
    ushort* Mcat = (ushort*)p; p += 2 * 96 * 192 * 2;
    if ((size_t)(p - ws) > ws_size) return;

    prep_kernel<<<81, 256, 0, stream>>>(qc_w, kvc_w, qt_w, kvt_w, cw, po_c, po_t, Wc, Wt, W1, W2, SSQ);
    ushort* QKVc;
    ushort* QKVt;
    if (merged) {
        QKVc = B2; QKVt = B3;
        conv_kernel<<<dim3(512, 2, 2), 256, 0, stream>>>(high, low, Wc, Wt, B0, B1);
        dwqk_kernel<<<dim3(8, 384, 2), 256, 0, stream>>>(B0, B1, qdw_c, kvdw_c, qdw_t, kvdw_t,
                                                         QKVc, QKVt, SSQ);
        gram_dwv_kernel<<<dim3(GNS + 256, 12), 256, 0, stream>>>(QKVc, QKVt, Gpart, B0, B1,
                                                                 kvdw_c, kvdw_t, GNS);
    } else {
        QKVc = B1; QKVt = B2;
        conv_kernel<<<dim3(512, 2, 1), 256, 0, stream>>>(high, high, Wc, Wc, B0, B0);
        dwfull_kernel<<<dim3(8, 576), 256, 0, stream>>>(B0, qdw_c, kvdw_c, QKVc, SSQ, 0);
        conv_kernel<<<dim3(512, 2, 1), 256, 0, stream>>>(low, low, Wt, Wt, B0, B0);
        dwfull_kernel<<<dim3(8, 576), 256, 0, stream>>>(B0, qdw_t, kvdw_t, QKVt, SSQ, 1);
        gram_dwv_kernel<<<dim3(GNS, 12), 256, 0, stream>>>(QKVc, QKVt, Gpart, B0, B0,
                                                           kvdw_c, kvdw_t, GNS);
    }
    attn_kernel<<<12, 256, 0, stream>>>(Gpart, SSQ, temp, W1, W2, Mcat);
    final_kernel<<<dim3(512, 2), 256, 0, stream>>>(QKVc, QKVt, Mcat, cb, out);
}

// Round 12
// 225.148 us; speedup vs baseline: 1.2893x; 1.0239x over previous
//
#include <hip/hip_runtime.h>
#include <hip/hip_bf16.h>

#define HW 65536
#define GNS 64

typedef __attribute__((ext_vector_type(8))) short short8;
typedef __attribute__((ext_vector_type(4))) float f32x4;
union U8 { short8 s; unsigned u[4]; ushort h[8]; };

static __device__ __forceinline__ ushort f2bf(float f) {
    union { float f; unsigned u; } v; v.f = f;
    unsigned u = v.u;
    unsigned r = (u + 0x7fffu + ((u >> 16) & 1u)) >> 16;
    return (ushort)r;
}
static __device__ __forceinline__ float bf2f(ushort u) {
    union { unsigned u; float f; } v; v.u = ((unsigned)u) << 16; return v.f;
}
static __device__ __forceinline__ unsigned pk2(float a, float b) {
    __hip_bfloat162 h = __float22bfloat162_rn(make_float2(a, b));
    union { __hip_bfloat162 h; unsigned u; } c; c.h = h; return c.u;
}
static __device__ __forceinline__ f32x4 mfma16(short8 a, short8 b, f32x4 c) {
    return __builtin_amdgcn_mfma_f32_16x16x32_bf16(a, b, c, 0, 0, 0);
}

// ---------------- prep: pack conv weights bf16; fold W1/W2; zero SSQ ----------------
__global__ __launch_bounds__(256) void prep_kernel(
        const float* __restrict__ qc, const float* __restrict__ kvc,
        const float* __restrict__ qt, const float* __restrict__ kvt,
        const float* __restrict__ cw, const float* __restrict__ poc, const float* __restrict__ pot,
        ushort* __restrict__ Wc, ushort* __restrict__ Wt,
        float* __restrict__ W1, float* __restrict__ W2, float* __restrict__ SSQ) {
    int bx = blockIdx.x, tid = threadIdx.x;
    if (bx < 9) {
        for (int idx = bx * 256 + tid; idx < 288 * 96; idx += 9 * 256) {
            Wc[idx] = f2bf(idx < 96 * 96 ? qc[idx] : kvc[idx - 96 * 96]);
            Wt[idx] = f2bf(idx < 96 * 96 ? qt[idx] : kvt[idx - 96 * 96]);
        }
        if (bx == 0)
            for (int idx = tid; idx < 8 * 96; idx += 256) SSQ[idx] = 0.f;
    } else {
        int idx = (bx - 9) * 256 + tid;          // 0..18431
        int sel = idx < 9216 ? 0 : 1;
        int i = sel ? idx - 9216 : idx;
        int o = i / 96, m = i % 96;
        const float* po = sel ? pot : poc;
        float acc = 0.f;
        for (int p = 0; p < 96; ++p)
            acc += cw[o * 192 + sel * 96 + p] * po[p * 96 + m];
        (sel ? W2 : W1)[i] = acc;
    }
}

// ================= conv body (device inline) =================
static __device__ __forceinline__ void conv_body(
        ushort xs[96][136], const float* __restrict__ X,
        const ushort* __restrict__ W, ushort* __restrict__ Y,
        int n0, int b, int tid) {
    int wave = tid >> 6, lane = tid & 63, lr = lane & 15, lg = lane >> 4;
    const float* Xb = X + (size_t)b * 96 * HW + n0;
    #pragma unroll
    for (int i = 0; i < 12; ++i) {
        int idx = tid + i * 256;
        int ch = idx >> 5, g = idx & 31;
        float4 v = *(const float4*)(Xb + (size_t)ch * HW + 4 * g);
        unsigned* d = (unsigned*)&xs[ch][4 * g];
        d[0] = pk2(v.x, v.y);
        d[1] = pk2(v.z, v.w);
    }
    __syncthreads();
    short8 af[2][3];
    #pragma unroll
    for (int nt = 0; nt < 2; ++nt) {
        int n = wave * 32 + nt * 16 + lr;
        #pragma unroll
        for (int kk = 0; kk < 3; ++kk) {
            int kb = kk * 32 + lg * 8;
            U8 t;
            #pragma unroll
            for (int j = 0; j < 4; ++j) {
                unsigned e0 = xs[kb + 2 * j][n];
                unsigned e1 = xs[kb + 2 * j + 1][n];
                t.u[j] = e0 | (e1 << 16);
            }
            af[nt][kk] = t.s;
        }
    }
    __syncthreads();
    ushort* ys = &xs[0][0];
    int row0 = tid >> 4, g = tid & 15;
    for (int og = 0; og < 3; ++og) {
        const ushort* Wg = W + (size_t)og * 96 * 96 + (size_t)lr * 96 + lg * 8;
        #pragma unroll
        for (int mt = 0; mt < 6; ++mt) {
            f32x4 a0 = {0.f, 0.f, 0.f, 0.f}, a1 = {0.f, 0.f, 0.f, 0.f};
            #pragma unroll
            for (int kk = 0; kk < 3; ++kk) {
                short8 wf = *(const short8*)(Wg + (size_t)mt * 16 * 96 + kk * 32);
                a0 = mfma16(af[0][kk], wf, a0);
                a1 = mfma16(af[1][kk], wf, a1);
            }
            unsigned* d0 = (unsigned*)&ys[(mt * 16 + lr) * 136 + wave * 32 + lg * 4];
            d0[0] = pk2(a0[0], a0[1]);
            d0[1] = pk2(a0[2], a0[3]);
            unsigned* d1 = (unsigned*)&ys[(mt * 16 + lr) * 136 + wave * 32 + 16 + lg * 4];
            d1[0] = pk2(a1[0], a1[1]);
            d1[1] = pk2(a1[2], a1[3]);
        }
        __syncthreads();
        ushort* Yg = Y + (size_t)(b * 288 + og * 96) * HW + n0;
        #pragma unroll
        for (int p = 0; p < 6; ++p) {
            int row = p * 16 + row0;
            *(short8*)&Yg[(size_t)row * HW + 8 * g] = *(const short8*)&ys[row * 136 + 8 * g];
        }
        __syncthreads();
    }
}

#define DW_LOADROW(R, D)                                                     \
{                                                                            \
    int r_ = (R);                                                            \
    if ((unsigned)r_ < 256u) {                                               \
        ushort4 t4 = *(const ushort4*)(src + r_ * 256 + 4 * lane);           \
        float c0 = bf2f(t4.x), c1 = bf2f(t4.y), c2 = bf2f(t4.z), c3 = bf2f(t4.w); \
        float lft = __shfl(c3, lane - 1);                                    \
        float rgt = __shfl(c0, lane + 1);                                    \
        if (lane == 0) lft = 0.f;                                            \
        if (lane == 63) rgt = 0.f;                                           \
        D[0] = lft; D[1] = c0; D[2] = c1; D[3] = c2; D[4] = c3; D[5] = rgt;  \
    } else {                                                                 \
        D[0] = 0.f; D[1] = 0.f; D[2] = 0.f; D[3] = 0.f; D[4] = 0.f; D[5] = 0.f; \
    }                                                                        \
}

// ================= depthwise body (device inline, all 288 ch) =================
static __device__ __forceinline__ void dw_body(
        const ushort* __restrict__ Y, const float* __restrict__ qdw,
        const float* __restrict__ kvdw, ushort* __restrict__ QKV,
        float* __restrict__ SSQ, int strm, int rg, int ch, int b, int tid) {
    int wave = tid >> 6, lane = tid & 63;
    int r0 = rg * 32 + wave * 8;
    const float* w = (ch < 96) ? (qdw + ch * 9) : (kvdw + (ch - 96) * 9);
    float w00 = w[0], w01 = w[1], w02 = w[2], w10 = w[3], w11 = w[4],
          w12 = w[5], w20 = w[6], w21 = w[7], w22 = w[8];
    const ushort* src = Y + (size_t)(b * 288 + ch) * HW;
    float rows[3][6];
    float ssq = 0.f;
    DW_LOADROW(r0 - 1, rows[0]);
    DW_LOADROW(r0, rows[1]);
    ushort* dst = QKV + (size_t)(b * 288 + ch) * HW;
    #pragma unroll
    for (int orow = 0; orow < 8; ++orow) {
        DW_LOADROW(r0 + orow + 1, rows[(orow + 2) % 3]);
        float* ra = rows[orow % 3];
        float* rb = rows[(orow + 1) % 3];
        float* rc = rows[(orow + 2) % 3];
        float acc[4];
        #pragma unroll
        for (int j = 0; j < 4; ++j) {
            acc[j] = w00 * ra[j] + w01 * ra[j + 1] + w02 * ra[j + 2]
                   + w10 * rb[j] + w11 * rb[j + 1] + w12 * rb[j + 2]
                   + w20 * rc[j] + w21 * rc[j + 1] + w22 * rc[j + 2];
            ssq += acc[j] * acc[j];
        }
        uint2 pv;
        pv.x = pk2(acc[0], acc[1]);
        pv.y = pk2(acc[2], acc[3]);
        *(uint2*)&dst[(r0 + orow) * 256 + 4 * lane] = pv;
    }
    if (ch < 192) {
        #pragma unroll
        for (int off = 1; off < 64; off <<= 1) ssq += __shfl_xor(ssq, off);
        if (lane == 0) {
            int t_ = ch >= 96;
            int chq = t_ ? ch - 96 : ch;
            int a_ = (strm == 0) ? t_ : (1 - t_);
            atomicAdd(&SSQ[((a_ * 2 + b) * 2 + t_) * 96 + chq], ssq);
        }
    }
}

// ---------------- conv (single stream) ----------------
__global__ __launch_bounds__(256, 2) void conv_kernel(const float* __restrict__ X,
                                                      const ushort* __restrict__ W,
                                                      ushort* __restrict__ Y) {
    __shared__ ushort xs[96][136];
    conv_body(xs, X, W, Y, blockIdx.x * 128, blockIdx.y, threadIdx.x);
}

// ---------------- merged: conv (stream t) + depthwise (stream c) ----------------
__global__ __launch_bounds__(256, 2) void convdw_kernel(
        const float* __restrict__ Xt, const ushort* __restrict__ Wt,
        ushort* __restrict__ Yt,
        const ushort* __restrict__ Yc, const float* __restrict__ qdw_c,
        const float* __restrict__ kvdw_c, ushort* __restrict__ QKVc,
        float* __restrict__ SSQ) {
    __shared__ ushort xs[96][136];
    int id = blockIdx.x, tid = threadIdx.x;
    if (id < 1024) {
        conv_body(xs, Xt, Wt, Yt, (id & 511) * 128, id >> 9, tid);
    } else {
        int f = id - 1024;                        // 0..4607
        int rg = f & 7, yy = f >> 3;
        dw_body(Yc, qdw_c, kvdw_c, QKVc, SSQ, 0, rg, yy % 288, yy / 288, tid);
    }
}

// ---------------- full depthwise (stream t) ----------------
__global__ __launch_bounds__(256, 8) void dwfull_kernel(
        const ushort* __restrict__ Y, const float* __restrict__ qdw,
        const float* __restrict__ kvdw, ushort* __restrict__ QKV,
        float* __restrict__ SSQ, int strm) {
    int yy = blockIdx.y;
    dw_body(Y, qdw, kvdw, QKV, SSQ, strm, blockIdx.x, yy % 288, yy / 288, threadIdx.x);
}

// ---------------- Gram: LDS-staged, XOR-swizzled, partials to Gpart ----------------
__global__ __launch_bounds__(256) void gram_kernel(const ushort* __restrict__ QKVc,
                                                   const ushort* __restrict__ QKVt,
                                                   float* __restrict__ Gpart) {
    __shared__ ushort qs[32 * 256];
    __shared__ ushort ks2[32 * 256];
    __shared__ float Gp[4][32][32];
    int tid = threadIdx.x, wave = tid >> 6, lane = tid & 63;
    int lr = lane & 15, lg = lane >> 4;
    int code = blockIdx.y;                        // a*6 + b*3 + h
    int a = code / 6, b = (code % 6) / 3, h = code % 3;
    const ushort* qsrc = (a == 0) ? QKVc : QKVt;
    const ushort* ksrc = (a == 0) ? QKVt : QKVc;
    const ushort* qb = qsrc + (size_t)(b * 288 + 32 * h) * HW + blockIdx.x * 1024;
    const ushort* kb = ksrc + (size_t)(b * 288 + 96 + 32 * h) * HW + blockIdx.x * 1024;
    f32x4 acc[2][2];
    #pragma unroll
    for (int i = 0; i < 2; ++i)
        #pragma unroll
        for (int j = 0; j < 2; ++j) acc[i][j] = (f32x4){0.f, 0.f, 0.f, 0.f};
    for (int ph = 0; ph < 4; ++ph) {
        int noff = ph * 256;
        #pragma unroll
        for (int i = 0; i < 4; ++i) {
            int idx = tid + i * 256;
            int row = idx >> 5, g = idx & 31;
            int col = (g * 8) ^ ((row & 7) << 3);
            *(short8*)&qs[row * 256 + col] = *(const short8*)(qb + (size_t)row * HW + noff + 8 * g);
            *(short8*)&ks2[row * 256 + col] = *(const short8*)(kb + (size_t)row * HW + noff + 8 * g);
        }
        __syncthreads();
        #pragma unroll
        for (int j = 0; j < 2; ++j) {
            int ks_ = wave * 2 + j;
            int c0 = (ks_ * 32 + lg * 8) ^ ((lr & 7) << 3);
            short8 a0 = *(const short8*)&qs[lr * 256 + c0];
            short8 a1 = *(const short8*)&qs[(16 + lr) * 256 + c0];
            short8 b0 = *(const short8*)&ks2[lr * 256 + c0];
            short8 b1 = *(const short8*)&ks2[(16 + lr) * 256 + c0];
            acc[0][0] = mfma16(a0, b0, acc[0][0]);
            acc[0][1] = mfma16(a0, b1, acc[0][1]);
            acc[1][0] = mfma16(a1, b0, acc[1][0]);
            acc[1][1] = mfma16(a1, b1, acc[1][1]);
        }
        __syncthreads();
    }
    #pragma unroll
    for (int i = 0; i < 2; ++i)
        #pragma unroll
        for (int j = 0; j < 2; ++j)
            #pragma unroll
            for (int r = 0; r < 4; ++r)
                Gp[wave][i * 16 + lg * 4 + r][j * 16 + lr] = acc[i][j][r];
    __syncthreads();
    float* Gout = Gpart + ((size_t)code * GNS + blockIdx.x) * 1024;
    for (int idx = tid; idx < 1024; idx += 256) {
        float ssum = 0.f;
        #pragma unroll
        for (int wv = 0; wv < 4; ++wv) ssum += (&Gp[wv][0][0])[idx];
        Gout[idx] = ssum;
    }
}

// ---------------- reduce partials + softmax + fold attn into M matrices ----------------
__global__ __launch_bounds__(256) void attn_kernel(const float* __restrict__ Gpart,
                                                   const float* __restrict__ SSQ,
                                                   const float* __restrict__ temperature,
                                                   const float* __restrict__ W1,
                                                   const float* __restrict__ W2,
                                                   ushort* __restrict__ Mcat) {
    __shared__ float Gs[1024];
    __shared__ float nq[32], nk[32], A[32][32];
    int tid = threadIdx.x;
    int code = blockIdx.x;
    int a = code / 6, b = (code % 6) / 3, h = code % 3;
    const float* gp = Gpart + (size_t)code * GNS * 1024;
    #pragma unroll
    for (int j = 0; j < 4; ++j) {
        int idx = tid + j * 256;
        float s = 0.f;
        #pragma unroll 16
        for (int p = 0; p < GNS; ++p) s += gp[(size_t)p * 1024 + idx];
        Gs[idx] = s;
    }
    if (tid < 32)
        nq[tid] = fmaxf(sqrtf(fmaxf(SSQ[((a * 2 + b) * 2 + 0) * 96 + 32 * h + tid], 0.f)), 1e-12f);
    else if (tid < 64)
        nk[tid - 32] = fmaxf(sqrtf(fmaxf(SSQ[((a * 2 + b) * 2 + 1) * 96 + 32 * h + (tid - 32)], 0.f)), 1e-12f);
    __syncthreads();
    if (tid < 32) {
        float t = temperature[h];
        float lgv[32];
        float inq = t / nq[tid];
        float mx = -1e30f;
        #pragma unroll
        for (int j = 0; j < 32; ++j) { lgv[j] = Gs[tid * 32 + j] * inq / nk[j]; mx = fmaxf(mx, lgv[j]); }
        float ssum = 0.f;
        #pragma unroll
        for (int j = 0; j < 32; ++j) { lgv[j] = expf(lgv[j] - mx); ssum += lgv[j]; }
        float inv = 1.f / ssum;
        #pragma unroll
        for (int j = 0; j < 32; ++j) A[tid][j] = lgv[j] * inv;
    }
    __syncthreads();
    const float* Wm = (a == 0) ? W1 : W2;
    for (int idx = tid; idx < 96 * 32; idx += 256) {
        int o = idx >> 5, d = idx & 31;
        float acc = 0.f;
        #pragma unroll
        for (int i = 0; i < 32; ++i)
            acc += Wm[o * 96 + 32 * h + i] * A[i][d];
        Mcat[(size_t)(b * 96 + o) * 192 + a * 96 + 32 * h + d] = f2bf(acc);
    }
}

// ---------------- final: K-split (half LDS), persistent acc, restaged stores ----------------
__global__ __launch_bounds__(256, 2) void final_kernel(const ushort* __restrict__ QKVc,
                                                       const ushort* __restrict__ QKVt,
                                                       const ushort* __restrict__ Mcat,
                                                       const float* __restrict__ bias,
                                                       float* __restrict__ out) {
    __shared__ float smem[48 * 132];              // 25344 B; aliased ushort[96][132]
    ushort* vs = (ushort*)smem;
    int tid = threadIdx.x;
    int n0 = blockIdx.x * 128, b = blockIdx.y;
    int wave = tid >> 6, lane = tid & 63, lr = lane & 15, lg = lane >> 4;
    f32x4 acc[6][2];
    #pragma unroll
    for (int mt = 0; mt < 6; ++mt) {
        acc[mt][0] = (f32x4){0.f, 0.f, 0.f, 0.f};
        acc[mt][1] = (f32x4){0.f, 0.f, 0.f, 0.f};
    }
    const ushort* Mb = Mcat + (size_t)b * 96 * 192;
    for (int half = 0; half < 2; ++half) {
        #pragma unroll
        for (int i = 0; i < 6; ++i) {
            int idx = tid + i * 256;              // 1536 = 96 d x 16 granules
            int dl = idx >> 4, g = idx & 15;
            int d = half * 96 + dl;
            const ushort* sp = (d < 96) ? (QKVt + (size_t)(b * 288 + 192 + d) * HW)
                                        : (QKVc + (size_t)(b * 288 + 192 + (d - 96)) * HW);
            U8 t;
            t.s = *(const short8*)(sp + n0 + 8 * g);
            unsigned* dst = (unsigned*)&vs[dl * 132 + 8 * g];
            dst[0] = t.u[0]; dst[1] = t.u[1]; dst[2] = t.u[2]; dst[3] = t.u[3];
        }
        __syncthreads();
        short8 vf[2][3];
        #pragma unroll
        for (int nt = 0; nt < 2; ++nt) {
            int n = wave * 32 + nt * 16 + lr;
            #pragma unroll
            for (int kk = 0; kk < 3; ++kk) {
                int kb = kk * 32 + lg * 8;
                U8 t;
                #pragma unroll
                for (int j = 0; j < 4; ++j) {
                    unsigned e0 = vs[(kb + 2 * j) * 132 + n];
                    unsigned e1 = vs[(kb + 2 * j + 1) * 132 + n];
                    t.u[j] = e0 | (e1 << 16);
                }
                vf[nt][kk] = t.s;
            }
        }
        __syncthreads();                          // vs reads done before next overwrite
        #pragma unroll
        for (int mt = 0; mt < 6; ++mt)
            #pragma unroll
            for (int kk = 0; kk < 3; ++kk) {
                short8 mf = *(const short8*)&Mb[(size_t)(mt * 16 + lr) * 192 + half * 96 + kk * 32 + lg * 8];
                acc[mt][0] = mfma16(vf[0][kk], mf, acc[mt][0]);
                acc[mt][1] = mfma16(vf[1][kk], mf, acc[mt][1]);
            }
    }
    float* outb = out + (size_t)b * 96 * HW + n0;
    #pragma unroll
    for (int half = 0; half < 2; ++half) {
        #pragma unroll
        for (int m = 0; m < 3; ++m) {
            int mt = half * 3 + m;
            *(float4*)&smem[(m * 16 + lr) * 132 + wave * 32 + lg * 4] =
                make_float4(acc[mt][0][0], acc[mt][0][1], acc[mt][0][2], acc[mt][0][3]);
            *(float4*)&smem[(m * 16 + lr) * 132 + wave * 32 + 16 + lg * 4] =
                make_float4(acc[mt][1][0], acc[mt][1][1], acc[mt][1][2], acc[mt][1][3]);
        }
        __syncthreads();
        #pragma unroll
        for (int i = 0; i < 6; ++i) {
            int idx = tid + i * 256;              // 1536 = 48 rows x 32 quads
            int row = idx >> 5, q = idx & 31;
            float4 v = *(const float4*)&smem[row * 132 + 4 * q];
            int grow = half * 48 + row;
            float bb = bias[grow];
            v.x += bb; v.y += bb; v.z += bb; v.w += bb;
            *(float4*)&outb[(size_t)grow * HW + 4 * q] = v;
        }
        __syncthreads();
    }
}

extern "C" void kernel_launch(void* const* d_in, const int* in_sizes, int n_in,
                              void* d_out, int out_size, void* d_ws, size_t ws_size,
                              hipStream_t stream) {
    const float* low    = (const float*)d_in[0];
    const float* high   = (const float*)d_in[1];
    const float* temp   = (const float*)d_in[2];
    const float* qc_w   = (const float*)d_in[3];
    const float* qdw_c  = (const float*)d_in[4];
    const float* kvc_w  = (const float*)d_in[5];
    const float* kvdw_c = (const float*)d_in[6];
    const float* qt_w   = (const float*)d_in[7];
    const float* qdw_t  = (const float*)d_in[8];
    const float* kvt_w  = (const float*)d_in[9];
    const float* kvdw_t = (const float*)d_in[10];
    const float* po_c   = (const float*)d_in[11];
    const float* po_t   = (const float*)d_in[12];
    const float* cw     = (const float*)d_in[13];
    const float* cb     = (const float*)d_in[14];
    float* out = (float*)d_out;

    char* ws = (char*)d_ws;
    const size_t SY = (size_t)2 * 288 * HW * 2;   // 75,497,472 B per big tensor
    ushort* B0 = (ushort*)(ws);                   // Yc, then QKVt (Yc dead after convdw)
    ushort* B1 = (ushort*)(ws + SY);              // Yt, then Gpart overlay (Yt dead after dw-t)
    ushort* B2 = (ushort*)(ws + 2 * SY);          // QKVc
    float* Gpart = (float*)B1;                    // 3.1 MB, overlays dead Yt
    char* p = ws + 3 * SY;
    ushort* Wc = (ushort*)p; p += 288 * 96 * 2;
    ushort* Wt = (ushort*)p; p += 288 * 96 * 2;
    float* W1  = (float*)p;  p += 96 * 96 * 4;
    float* W2  = (float*)p;  p += 96 * 96 * 4;
    float* SSQ = (float*)p;  p += 8 * 96 * 4;
    ushort* Mcat = (ushort*)p; p += 2 * 96 * 192 * 2;
    if ((size_t)(p - ws) > ws_size) return;

    ushort* Yc   = B0;
    ushort* Yt   = B1;
    ushort* QKVc = B2;
    ushort* QKVt = B0;                            // overwrites Yc after it is consumed

    prep_kernel<<<81, 256, 0, stream>>>(qc_w, kvc_w, qt_w, kvt_w, cw, po_c, po_t, Wc, Wt, W1, W2, SSQ);
    // 1) conv stream c: high -> Yc (B0)
    conv_kernel<<<dim3(512, 2), 256, 0, stream>>>(high, Wc, Yc);
    // 2) overlap: conv stream t (low -> Yt/B1)  ||  dw stream c (Yc/B0 -> QKVc/B2)
    convdw_kernel<<<5632, 256, 0, stream>>>(low, Wt, Yt, Yc, qdw_c, kvdw_c, QKVc, SSQ);
    // 3) dw stream t: Yt (B1) -> QKVt (B0)
    dwfull_kernel<<<dim3(8, 576), 256, 0, stream>>>(Yt, qdw_t, kvdw_t, QKVt, SSQ, 1);
    // 4) gram: QKVc (B2) x QKVt (B0) -> Gpart (B1)
    gram_kernel<<<dim3(GNS, 12), 256, 0, stream>>>(QKVc, QKVt, Gpart);
    attn_kernel<<<12, 256, 0, stream>>>(Gpart, SSQ, temp, W1, W2, Mcat);
    final_kernel<<<dim3(512, 2), 256, 0, stream>>>(QKVc, QKVt, Mcat, cb, out);
}